// Round 1
// baseline (3215.099 us; speedup 1.0000x reference)
//
#include <hip/hip_runtime.h>
#include <math.h>

#define N_NODES 100000
#define N_EDGES 100000
#define NNZT    1600000
#define C       128

// K1: t_node[i] = dot(x_0[i], a_tgt)   (a_tgt = att_weight[128..255])
__global__ __launch_bounds__(128) void k1_node_dot(
    const float* __restrict__ x0, const float* __restrict__ att,
    float* __restrict__ t_node)
{
    int node = blockIdx.x;
    int tid  = threadIdx.x;                // 128 threads = 2 waves
    float v = x0[(size_t)node * C + tid] * att[C + tid];
    #pragma unroll
    for (int off = 32; off > 0; off >>= 1) v += __shfl_down(v, off, 64);
    __shared__ float w0, w1;
    if (tid == 0)  w0 = v;
    if (tid == 64) w1 = v;
    __syncthreads();
    if (tid == 0) t_node[node] = w0 + w1;
}

// K2: per-edge segment sum over sorted edge_idx -> m_0_1 row, plus
//     s_edge[j] = dot(m_0_1[j], a_src)   (a_src = att_weight[0..127])
__global__ __launch_bounds__(128) void k2_edge_msg(
    const float* __restrict__ x0,
    const int*   __restrict__ node_idx,
    const int*   __restrict__ edge_idx,
    const float* __restrict__ values,
    const float* __restrict__ att,
    float* __restrict__ m01,
    float* __restrict__ s_edge)
{
    int j   = blockIdx.x;
    int tid = threadIdx.x;                 // 128 threads, one per channel
    __shared__ int seg[2];
    if (tid == 0) {
        int lo = 0, hi = NNZT;
        while (lo < hi) { int mid = (lo + hi) >> 1; if (edge_idx[mid] <  j) lo = mid + 1; else hi = mid; }
        seg[0] = lo;
        hi = NNZT;
        while (lo < hi) { int mid = (lo + hi) >> 1; if (edge_idx[mid] <= j) lo = mid + 1; else hi = mid; }
        seg[1] = lo;
    }
    __syncthreads();
    int start = seg[0], end = seg[1];
    float acc = 0.f;
    for (int e = start; e < end; ++e) {
        int n = node_idx[e];
        acc += values[e] * x0[(size_t)n * C + tid];   // coalesced 512B row read
    }
    m01[(size_t)j * C + tid] = acc;
    float v = acc * att[tid];
    #pragma unroll
    for (int off = 32; off > 0; off >>= 1) v += __shfl_down(v, off, 64);
    __shared__ float w0, w1;
    if (tid == 0)  w0 = v;
    if (tid == 64) w1 = v;
    __syncthreads();
    if (tid == 0) s_edge[j] = w0 + w1;
}

// K3: y[node_idx[e]] += elu(s_edge[edge_idx[e]] + t_node[node_idx[e]]) * values[e]
//                       * m_0_1[edge_idx[e]]     (atomic scatter, 32 thr/nnz x 4 ch)
__global__ __launch_bounds__(256) void k3_scatter(
    const float* __restrict__ m01,
    const int*   __restrict__ node_idx,
    const int*   __restrict__ edge_idx,
    const float* __restrict__ values,
    const float* __restrict__ s_edge,
    const float* __restrict__ t_node,
    float* __restrict__ y)
{
    long long gid = (long long)blockIdx.x * blockDim.x + threadIdx.x;
    int e = (int)(gid >> 5);
    if (e >= NNZT) return;
    int cg = ((int)gid & 31) << 2;
    int j = edge_idx[e];
    int n = node_idx[e];
    float s    = s_edge[j] + t_node[n];
    float sc   = s > 0.f ? s : expm1f(s);     // elu, alpha=1
    float coef = sc * values[e];
    float4 m4 = *reinterpret_cast<const float4*>(m01 + (size_t)j * C + cg);
    float* yr = y + (size_t)n * C + cg;
    atomicAdd(yr + 0, coef * m4.x);
    atomicAdd(yr + 1, coef * m4.y);
    atomicAdd(yr + 2, coef * m4.z);
    atomicAdd(yr + 3, coef * m4.w);
}

// K4: out = y @ W    (100000x128 @ 128x128, fp32 vector ALU, W staged in LDS)
__global__ __launch_bounds__(256) void k4_gemm(
    const float* __restrict__ y,
    const float* __restrict__ W,
    float* __restrict__ out)
{
    __shared__ float Wl[C * C];     // 64 KB
    __shared__ float yl[32 * C];    // 16 KB
    int tid = threadIdx.x;
    int rowbase = blockIdx.x * 32;  // N_NODES % 32 == 0
    for (int i = tid; i < C * C / 4; i += 256)
        reinterpret_cast<float4*>(Wl)[i] = reinterpret_cast<const float4*>(W)[i];
    for (int i = tid; i < 32 * C / 4; i += 256) {
        int r = i >> 5;             // 32 float4 per row
        reinterpret_cast<float4*>(yl)[i] =
            reinterpret_cast<const float4*>(y + (size_t)(rowbase + r) * C)[i & 31];
    }
    __syncthreads();
    int r8 = tid >> 5;              // 0..7
    int cg = (tid & 31) << 2;       // col group of 4
    float4 acc[4];
    #pragma unroll
    for (int rr = 0; rr < 4; ++rr) acc[rr] = make_float4(0.f, 0.f, 0.f, 0.f);
    for (int k = 0; k < C; ++k) {
        float4 w4 = *reinterpret_cast<const float4*>(&Wl[k * C + cg]);
        #pragma unroll
        for (int rr = 0; rr < 4; ++rr) {
            float yv = yl[(r8 + rr * 8) * C + k];   // broadcast within wave
            acc[rr].x += yv * w4.x;
            acc[rr].y += yv * w4.y;
            acc[rr].z += yv * w4.z;
            acc[rr].w += yv * w4.w;
        }
    }
    #pragma unroll
    for (int rr = 0; rr < 4; ++rr) {
        int r = rowbase + r8 + rr * 8;
        *reinterpret_cast<float4*>(&out[(size_t)r * C + cg]) = acc[rr];
    }
}

extern "C" void kernel_launch(void* const* d_in, const int* in_sizes, int n_in,
                              void* d_out, int out_size, void* d_ws, size_t ws_size,
                              hipStream_t stream)
{
    const float* x0       = (const float*)d_in[0];
    const int*   node_idx = (const int*)  d_in[1];
    const int*   edge_idx = (const int*)  d_in[2];
    const float* values   = (const float*)d_in[3];
    const float* W        = (const float*)d_in[4];
    const float* att      = (const float*)d_in[5];
    float* out = (float*)d_out;

    // m_0_1 (N_EDGES*C) lives in d_out: dead before K4 overwrites d_out.
    float* m01 = out;
    char*  ws  = (char*)d_ws;
    float* y      = (float*)ws;                                   // N_NODES*C
    float* t_node = (float*)(ws + (size_t)N_NODES * C * sizeof(float));
    float* s_edge = t_node + N_NODES;

    hipMemsetAsync(y, 0, (size_t)N_NODES * C * sizeof(float), stream);
    k1_node_dot<<<N_NODES, 128, 0, stream>>>(x0, att, t_node);
    k2_edge_msg<<<N_EDGES, 128, 0, stream>>>(x0, node_idx, edge_idx, values, att, m01, s_edge);
    k3_scatter<<<(NNZT * 32 + 255) / 256, 256, 0, stream>>>(m01, node_idx, edge_idx, values,
                                                            s_edge, t_node, y);
    k4_gemm<<<N_NODES / 32, 256, 0, stream>>>(y, W, out);
}

// Round 2
// 899.209 us; speedup vs baseline: 3.5755x; 3.5755x over previous
//
#include <hip/hip_runtime.h>
#include <math.h>

#define N_NODES 100000
#define N_EDGES 100000
#define NNZT    1600000
#define C       128
#define NBLK_SCAN ((N_NODES + 255) / 256)   // 391

// K1: t_node[i] = dot(x_0[i], a_tgt)
__global__ __launch_bounds__(128) void k1_node_dot(
    const float* __restrict__ x0, const float* __restrict__ att,
    float* __restrict__ t_node)
{
    int node = blockIdx.x;
    int tid  = threadIdx.x;
    float v = x0[(size_t)node * C + tid] * att[C + tid];
    #pragma unroll
    for (int off = 32; off > 0; off >>= 1) v += __shfl_down(v, off, 64);
    __shared__ float w0, w1;
    if (tid == 0)  w0 = v;
    if (tid == 64) w1 = v;
    __syncthreads();
    if (tid == 0) t_node[node] = w0 + w1;
}

// K2: per-edge segment sum over sorted edge_idx -> m_0_1 row, + s_edge dot
__global__ __launch_bounds__(128) void k2_edge_msg(
    const float* __restrict__ x0,
    const int*   __restrict__ node_idx,
    const int*   __restrict__ edge_idx,
    const float* __restrict__ values,
    const float* __restrict__ att,
    float* __restrict__ m01,
    float* __restrict__ s_edge)
{
    int j   = blockIdx.x;
    int tid = threadIdx.x;
    __shared__ int seg[2];
    if (tid == 0) {
        int lo = 0, hi = NNZT;
        while (lo < hi) { int mid = (lo + hi) >> 1; if (edge_idx[mid] <  j) lo = mid + 1; else hi = mid; }
        seg[0] = lo;
        hi = NNZT;
        while (lo < hi) { int mid = (lo + hi) >> 1; if (edge_idx[mid] <= j) lo = mid + 1; else hi = mid; }
        seg[1] = lo;
    }
    __syncthreads();
    int start = seg[0], end = seg[1];
    float acc = 0.f;
    for (int e = start; e < end; ++e) {
        int n = node_idx[e];
        acc += values[e] * x0[(size_t)n * C + tid];
    }
    m01[(size_t)j * C + tid] = acc;
    float v = acc * att[tid];
    #pragma unroll
    for (int off = 32; off > 0; off >>= 1) v += __shfl_down(v, off, 64);
    __shared__ float w0, w1;
    if (tid == 0)  w0 = v;
    if (tid == 64) w1 = v;
    __syncthreads();
    if (tid == 0) s_edge[j] = w0 + w1;
}

// H: histogram of node_idx
__global__ __launch_bounds__(256) void k_hist(
    const int* __restrict__ node_idx, int* __restrict__ count)
{
    int e = blockIdx.x * 256 + threadIdx.x;
    if (e < NNZT) atomicAdd(&count[node_idx[e]], 1);
}

// S1: per-256-chunk sums
__global__ __launch_bounds__(256) void k_scan1(
    const int* __restrict__ count, int* __restrict__ bsum)
{
    __shared__ int s[256];
    int tid = threadIdx.x;
    int i = blockIdx.x * 256 + tid;
    s[tid] = (i < N_NODES) ? count[i] : 0;
    __syncthreads();
    #pragma unroll
    for (int off = 128; off > 0; off >>= 1) {
        if (tid < off) s[tid] += s[tid + off];
        __syncthreads();
    }
    if (tid == 0) bsum[blockIdx.x] = s[0];
}

// S2: exclusive scan of block sums (single block, nb <= 512)
__global__ __launch_bounds__(512) void k_scan2(int* __restrict__ bsum)
{
    __shared__ int s[512];
    int tid = threadIdx.x;
    int v = (tid < NBLK_SCAN) ? bsum[tid] : 0;
    s[tid] = v;
    __syncthreads();
    for (int off = 1; off < 512; off <<= 1) {
        int t = (tid >= off) ? s[tid - off] : 0;
        __syncthreads();
        s[tid] += t;
        __syncthreads();
    }
    if (tid < NBLK_SCAN) bsum[tid] = s[tid] - v;   // exclusive
}

// S3: in-chunk exclusive scan + block offset -> base, cursor
__global__ __launch_bounds__(256) void k_scan3(
    const int* __restrict__ count, const int* __restrict__ bsum,
    int* __restrict__ base, int* __restrict__ cursor)
{
    __shared__ int s[256];
    int tid = threadIdx.x;
    int i = blockIdx.x * 256 + tid;
    int v = (i < N_NODES) ? count[i] : 0;
    s[tid] = v;
    __syncthreads();
    for (int off = 1; off < 256; off <<= 1) {
        int t = (tid >= off) ? s[tid - off] : 0;
        __syncthreads();
        s[tid] += t;
        __syncthreads();
    }
    if (i < N_NODES) {
        int excl = s[tid] - v + bsum[blockIdx.x];
        base[i]   = excl;
        cursor[i] = excl;
    }
}

// F: scatter edges into CSR order, precomputing coef = elu(s_j + t_n) * v_e
__global__ __launch_bounds__(256) void k_fill(
    const int*   __restrict__ node_idx,
    const int*   __restrict__ edge_idx,
    const float* __restrict__ values,
    const float* __restrict__ s_edge,
    const float* __restrict__ t_node,
    int*   __restrict__ cursor,
    int*   __restrict__ jarr,
    float* __restrict__ carr)
{
    int e = blockIdx.x * 256 + threadIdx.x;
    if (e >= NNZT) return;
    int n = node_idx[e];
    int j = edge_idx[e];
    float s = s_edge[j] + t_node[n];
    float coef = (s > 0.f ? s : expm1f(s)) * values[e];
    int pos = atomicAdd(&cursor[n], 1);
    jarr[pos] = j;
    carr[pos] = coef;
}

// K3: gather-accumulate per destination node (atomic-free)
__global__ __launch_bounds__(128) void k3_gather(
    const float* __restrict__ m01,
    const int*   __restrict__ jarr,
    const float* __restrict__ carr,
    const int*   __restrict__ base,
    const int*   __restrict__ count,
    float* __restrict__ y)
{
    int n   = blockIdx.x;
    int tid = threadIdx.x;
    int b   = base[n];
    int cnt = count[n];
    float acc = 0.f;
    for (int i = 0; i < cnt; ++i) {
        int   j    = jarr[b + i];   // broadcast (same addr all lanes)
        float coef = carr[b + i];
        acc += coef * m01[(size_t)j * C + tid];  // coalesced 512B row
    }
    y[(size_t)n * C + tid] = acc;
}

// K4: out = y @ W
__global__ __launch_bounds__(256) void k4_gemm(
    const float* __restrict__ y,
    const float* __restrict__ W,
    float* __restrict__ out)
{
    __shared__ float Wl[C * C];
    __shared__ float yl[32 * C];
    int tid = threadIdx.x;
    int rowbase = blockIdx.x * 32;
    for (int i = tid; i < C * C / 4; i += 256)
        reinterpret_cast<float4*>(Wl)[i] = reinterpret_cast<const float4*>(W)[i];
    for (int i = tid; i < 32 * C / 4; i += 256) {
        int r = i >> 5;
        reinterpret_cast<float4*>(yl)[i] =
            reinterpret_cast<const float4*>(y + (size_t)(rowbase + r) * C)[i & 31];
    }
    __syncthreads();
    int r8 = tid >> 5;
    int cg = (tid & 31) << 2;
    float4 acc[4];
    #pragma unroll
    for (int rr = 0; rr < 4; ++rr) acc[rr] = make_float4(0.f, 0.f, 0.f, 0.f);
    for (int k = 0; k < C; ++k) {
        float4 w4 = *reinterpret_cast<const float4*>(&Wl[k * C + cg]);
        #pragma unroll
        for (int rr = 0; rr < 4; ++rr) {
            float yv = yl[(r8 + rr * 8) * C + k];
            acc[rr].x += yv * w4.x;
            acc[rr].y += yv * w4.y;
            acc[rr].z += yv * w4.z;
            acc[rr].w += yv * w4.w;
        }
    }
    #pragma unroll
    for (int rr = 0; rr < 4; ++rr) {
        int r = rowbase + r8 + rr * 8;
        *reinterpret_cast<float4*>(&out[(size_t)r * C + cg]) = acc[rr];
    }
}

extern "C" void kernel_launch(void* const* d_in, const int* in_sizes, int n_in,
                              void* d_out, int out_size, void* d_ws, size_t ws_size,
                              hipStream_t stream)
{
    const float* x0       = (const float*)d_in[0];
    const int*   node_idx = (const int*)  d_in[1];
    const int*   edge_idx = (const int*)  d_in[2];
    const float* values   = (const float*)d_in[3];
    const float* W        = (const float*)d_in[4];
    const float* att      = (const float*)d_in[5];
    float* out = (float*)d_out;

    // m_0_1 (N_EDGES*C) lives in d_out: dead before K4 overwrites d_out.
    float* m01 = out;
    char*  p   = (char*)d_ws;
    float* y      = (float*)p;  p += (size_t)N_NODES * C * sizeof(float); // 51.2 MB
    float* t_node = (float*)p;  p += N_NODES * sizeof(float);
    float* s_edge = (float*)p;  p += N_EDGES * sizeof(float);
    int*   count  = (int*)p;    p += N_NODES * sizeof(int);
    int*   base   = (int*)p;    p += N_NODES * sizeof(int);
    int*   cursor = (int*)p;    p += N_NODES * sizeof(int);
    int*   bsum   = (int*)p;    p += 512 * sizeof(int);
    int*   jarr   = (int*)p;    p += (size_t)NNZT * sizeof(int);          // 6.4 MB
    float* carr   = (float*)p;  p += (size_t)NNZT * sizeof(float);        // 6.4 MB

    hipMemsetAsync(count, 0, N_NODES * sizeof(int), stream);

    k1_node_dot<<<N_NODES, 128, 0, stream>>>(x0, att, t_node);
    k2_edge_msg<<<N_EDGES, 128, 0, stream>>>(x0, node_idx, edge_idx, values, att, m01, s_edge);

    k_hist <<<(NNZT + 255) / 256, 256, 0, stream>>>(node_idx, count);
    k_scan1<<<NBLK_SCAN, 256, 0, stream>>>(count, bsum);
    k_scan2<<<1, 512, 0, stream>>>(bsum);
    k_scan3<<<NBLK_SCAN, 256, 0, stream>>>(count, bsum, base, cursor);
    k_fill <<<(NNZT + 255) / 256, 256, 0, stream>>>(node_idx, edge_idx, values,
                                                    s_edge, t_node, cursor, jarr, carr);

    k3_gather<<<N_NODES, 128, 0, stream>>>(m01, jarr, carr, base, count, y);
    k4_gemm<<<N_NODES / 32, 256, 0, stream>>>(y, W, out);
}

// Round 3
// 707.056 us; speedup vs baseline: 4.5472x; 1.2718x over previous
//
#include <hip/hip_runtime.h>
#include <math.h>

#define N_NODES 100000
#define N_EDGES 100000
#define NNZT    1600000
#define C       128
#define NBLK_SCAN ((N_NODES + 255) / 256)   // 391

// K1: t_node[i] = dot(x_0[i], a_tgt)
__global__ __launch_bounds__(128) void k1_node_dot(
    const float* __restrict__ x0, const float* __restrict__ att,
    float* __restrict__ t_node)
{
    int node = blockIdx.x;
    int tid  = threadIdx.x;
    float v = x0[(size_t)node * C + tid] * att[C + tid];
    #pragma unroll
    for (int off = 32; off > 0; off >>= 1) v += __shfl_down(v, off, 64);
    __shared__ float w0, w1;
    if (tid == 0)  w0 = v;
    if (tid == 64) w1 = v;
    __syncthreads();
    if (tid == 0) t_node[node] = w0 + w1;
}

// K2: segment sum over sorted edge_idx -> m_0_1 row (+ s_edge dot).
// 128 thr = 4 edge-slots x 32 lanes x float4; 2x unroll -> 8 rows in flight.
__global__ __launch_bounds__(128) void k2_edge_msg(
    const float* __restrict__ x0,
    const int*   __restrict__ node_idx,
    const int*   __restrict__ edge_idx,
    const float* __restrict__ values,
    const float* __restrict__ att,
    float* __restrict__ m01,
    float* __restrict__ s_edge)
{
    int j   = blockIdx.x;
    int tid = threadIdx.x;
    int sub = tid >> 5;             // 0..3 edge slot
    int cg  = (tid & 31) << 2;      // channel group (float4)
    __shared__ int seg[2];
    if (tid == 0) {
        int lo = 0, hi = NNZT;
        while (lo < hi) { int mid = (lo + hi) >> 1; if (edge_idx[mid] <  j) lo = mid + 1; else hi = mid; }
        seg[0] = lo;
        hi = NNZT;
        while (lo < hi) { int mid = (lo + hi) >> 1; if (edge_idx[mid] <= j) lo = mid + 1; else hi = mid; }
        seg[1] = lo;
    }
    __syncthreads();
    int start = seg[0], end = seg[1];

    float4 acc = make_float4(0.f, 0.f, 0.f, 0.f);
    int e = start + sub;
    for (; e + 4 < end; e += 8) {
        int   n0 = node_idx[e];
        int   n1 = node_idx[e + 4];
        float v0 = values[e];
        float v1 = values[e + 4];
        float4 xa = *reinterpret_cast<const float4*>(x0 + (size_t)n0 * C + cg);
        float4 xb = *reinterpret_cast<const float4*>(x0 + (size_t)n1 * C + cg);
        acc.x += v0 * xa.x + v1 * xb.x;
        acc.y += v0 * xa.y + v1 * xb.y;
        acc.z += v0 * xa.z + v1 * xb.z;
        acc.w += v0 * xa.w + v1 * xb.w;
    }
    if (e < end) {
        int   n = node_idx[e];
        float v = values[e];
        float4 xa = *reinterpret_cast<const float4*>(x0 + (size_t)n * C + cg);
        acc.x += v * xa.x; acc.y += v * xa.y; acc.z += v * xa.z; acc.w += v * xa.w;
    }

    __shared__ float4 red[128];
    red[tid] = acc;
    __syncthreads();
    if (tid < 32) {
        float4 a = red[tid], b = red[tid + 32], c = red[tid + 64], d = red[tid + 96];
        float4 s;
        s.x = a.x + b.x + c.x + d.x;
        s.y = a.y + b.y + c.y + d.y;
        s.z = a.z + b.z + c.z + d.z;
        s.w = a.w + b.w + c.w + d.w;
        *reinterpret_cast<float4*>(m01 + (size_t)j * C + cg) = s;
        float4 aw = *reinterpret_cast<const float4*>(att + cg);
        float p = s.x * aw.x + s.y * aw.y + s.z * aw.z + s.w * aw.w;
        #pragma unroll
        for (int off = 16; off > 0; off >>= 1) p += __shfl_down(p, off, 64);
        if (tid == 0) s_edge[j] = p;
    }
}

// H: histogram of node_idx
__global__ __launch_bounds__(256) void k_hist(
    const int* __restrict__ node_idx, int* __restrict__ count)
{
    int e = blockIdx.x * 256 + threadIdx.x;
    if (e < NNZT) atomicAdd(&count[node_idx[e]], 1);
}

// S1: per-256-chunk sums
__global__ __launch_bounds__(256) void k_scan1(
    const int* __restrict__ count, int* __restrict__ bsum)
{
    __shared__ int s[256];
    int tid = threadIdx.x;
    int i = blockIdx.x * 256 + tid;
    s[tid] = (i < N_NODES) ? count[i] : 0;
    __syncthreads();
    #pragma unroll
    for (int off = 128; off > 0; off >>= 1) {
        if (tid < off) s[tid] += s[tid + off];
        __syncthreads();
    }
    if (tid == 0) bsum[blockIdx.x] = s[0];
}

// S2: exclusive scan of block sums (single block, nb <= 512)
__global__ __launch_bounds__(512) void k_scan2(int* __restrict__ bsum)
{
    __shared__ int s[512];
    int tid = threadIdx.x;
    int v = (tid < NBLK_SCAN) ? bsum[tid] : 0;
    s[tid] = v;
    __syncthreads();
    for (int off = 1; off < 512; off <<= 1) {
        int t = (tid >= off) ? s[tid - off] : 0;
        __syncthreads();
        s[tid] += t;
        __syncthreads();
    }
    if (tid < NBLK_SCAN) bsum[tid] = s[tid] - v;   // exclusive
}

// S3: in-chunk exclusive scan + block offset -> base, cursor
__global__ __launch_bounds__(256) void k_scan3(
    const int* __restrict__ count, const int* __restrict__ bsum,
    int* __restrict__ base, int* __restrict__ cursor)
{
    __shared__ int s[256];
    int tid = threadIdx.x;
    int i = blockIdx.x * 256 + tid;
    int v = (i < N_NODES) ? count[i] : 0;
    s[tid] = v;
    __syncthreads();
    for (int off = 1; off < 256; off <<= 1) {
        int t = (tid >= off) ? s[tid - off] : 0;
        __syncthreads();
        s[tid] += t;
        __syncthreads();
    }
    if (i < N_NODES) {
        int excl = s[tid] - v + bsum[blockIdx.x];
        base[i]   = excl;
        cursor[i] = excl;
    }
}

// F: scatter edges into CSR order; coef = elu(s_j + t_n) * v_e packed with j
__global__ __launch_bounds__(256) void k_fill(
    const int*   __restrict__ node_idx,
    const int*   __restrict__ edge_idx,
    const float* __restrict__ values,
    const float* __restrict__ s_edge,
    const float* __restrict__ t_node,
    int*   __restrict__ cursor,
    int2*  __restrict__ jc)
{
    int e = blockIdx.x * 256 + threadIdx.x;
    if (e >= NNZT) return;
    int n = node_idx[e];
    int j = edge_idx[e];
    float s = s_edge[j] + t_node[n];
    float coef = (s > 0.f ? s : expm1f(s)) * values[e];
    int pos = atomicAdd(&cursor[n], 1);
    jc[pos] = make_int2(j, __float_as_int(coef));
}

// K3: gather-accumulate per destination node (atomic-free), 8 rows in flight
__global__ __launch_bounds__(128) void k3_gather(
    const float* __restrict__ m01,
    const int2*  __restrict__ jc,
    const int*   __restrict__ base,
    const int*   __restrict__ count,
    float* __restrict__ y)
{
    int n   = blockIdx.x;
    int tid = threadIdx.x;
    int sub = tid >> 5;
    int cg  = (tid & 31) << 2;
    int b   = base[n];
    int cnt = count[n];

    float4 acc = make_float4(0.f, 0.f, 0.f, 0.f);
    int i = sub;
    for (; i + 4 < cnt; i += 8) {
        int2 p0 = jc[b + i];
        int2 p1 = jc[b + i + 4];
        float c0 = __int_as_float(p0.y);
        float c1 = __int_as_float(p1.y);
        float4 ma = *reinterpret_cast<const float4*>(m01 + (size_t)p0.x * C + cg);
        float4 mb = *reinterpret_cast<const float4*>(m01 + (size_t)p1.x * C + cg);
        acc.x += c0 * ma.x + c1 * mb.x;
        acc.y += c0 * ma.y + c1 * mb.y;
        acc.z += c0 * ma.z + c1 * mb.z;
        acc.w += c0 * ma.w + c1 * mb.w;
    }
    if (i < cnt) {
        int2 p0 = jc[b + i];
        float c0 = __int_as_float(p0.y);
        float4 ma = *reinterpret_cast<const float4*>(m01 + (size_t)p0.x * C + cg);
        acc.x += c0 * ma.x; acc.y += c0 * ma.y; acc.z += c0 * ma.z; acc.w += c0 * ma.w;
    }

    __shared__ float4 red[128];
    red[tid] = acc;
    __syncthreads();
    if (tid < 32) {
        float4 a = red[tid], bb = red[tid + 32], c = red[tid + 64], d = red[tid + 96];
        float4 s;
        s.x = a.x + bb.x + c.x + d.x;
        s.y = a.y + bb.y + c.y + d.y;
        s.z = a.z + bb.z + c.z + d.z;
        s.w = a.w + bb.w + c.w + d.w;
        *reinterpret_cast<float4*>(y + (size_t)n * C + cg) = s;
    }
}

// K4: out = y @ W
__global__ __launch_bounds__(256) void k4_gemm(
    const float* __restrict__ y,
    const float* __restrict__ W,
    float* __restrict__ out)
{
    __shared__ float Wl[C * C];
    __shared__ float yl[32 * C];
    int tid = threadIdx.x;
    int rowbase = blockIdx.x * 32;
    for (int i = tid; i < C * C / 4; i += 256)
        reinterpret_cast<float4*>(Wl)[i] = reinterpret_cast<const float4*>(W)[i];
    for (int i = tid; i < 32 * C / 4; i += 256) {
        int r = i >> 5;
        reinterpret_cast<float4*>(yl)[i] =
            reinterpret_cast<const float4*>(y + (size_t)(rowbase + r) * C)[i & 31];
    }
    __syncthreads();
    int r8 = tid >> 5;
    int cg = (tid & 31) << 2;
    float4 acc[4];
    #pragma unroll
    for (int rr = 0; rr < 4; ++rr) acc[rr] = make_float4(0.f, 0.f, 0.f, 0.f);
    for (int k = 0; k < C; ++k) {
        float4 w4 = *reinterpret_cast<const float4*>(&Wl[k * C + cg]);
        #pragma unroll
        for (int rr = 0; rr < 4; ++rr) {
            float yv = yl[(r8 + rr * 8) * C + k];
            acc[rr].x += yv * w4.x;
            acc[rr].y += yv * w4.y;
            acc[rr].z += yv * w4.z;
            acc[rr].w += yv * w4.w;
        }
    }
    #pragma unroll
    for (int rr = 0; rr < 4; ++rr) {
        int r = rowbase + r8 + rr * 8;
        *reinterpret_cast<float4*>(&out[(size_t)r * C + cg]) = acc[rr];
    }
}

extern "C" void kernel_launch(void* const* d_in, const int* in_sizes, int n_in,
                              void* d_out, int out_size, void* d_ws, size_t ws_size,
                              hipStream_t stream)
{
    const float* x0       = (const float*)d_in[0];
    const int*   node_idx = (const int*)  d_in[1];
    const int*   edge_idx = (const int*)  d_in[2];
    const float* values   = (const float*)d_in[3];
    const float* W        = (const float*)d_in[4];
    const float* att      = (const float*)d_in[5];
    float* out = (float*)d_out;

    // m_0_1 (N_EDGES*C) lives in d_out: dead before K4 overwrites d_out.
    float* m01 = out;
    char*  p   = (char*)d_ws;
    float* y      = (float*)p;  p += (size_t)N_NODES * C * sizeof(float); // 51.2 MB
    float* t_node = (float*)p;  p += N_NODES * sizeof(float);
    float* s_edge = (float*)p;  p += N_EDGES * sizeof(float);
    int*   count  = (int*)p;    p += N_NODES * sizeof(int);
    int*   base   = (int*)p;    p += N_NODES * sizeof(int);
    int*   cursor = (int*)p;    p += N_NODES * sizeof(int);
    int*   bsum   = (int*)p;    p += 512 * sizeof(int);
    int2*  jc     = (int2*)p;   p += (size_t)NNZT * sizeof(int2);         // 12.8 MB

    hipMemsetAsync(count, 0, N_NODES * sizeof(int), stream);

    k1_node_dot<<<N_NODES, 128, 0, stream>>>(x0, att, t_node);
    k2_edge_msg<<<N_EDGES, 128, 0, stream>>>(x0, node_idx, edge_idx, values, att, m01, s_edge);

    k_hist <<<(NNZT + 255) / 256, 256, 0, stream>>>(node_idx, count);
    k_scan1<<<NBLK_SCAN, 256, 0, stream>>>(count, bsum);
    k_scan2<<<1, 512, 0, stream>>>(bsum);
    k_scan3<<<NBLK_SCAN, 256, 0, stream>>>(count, bsum, base, cursor);
    k_fill <<<(NNZT + 255) / 256, 256, 0, stream>>>(node_idx, edge_idx, values,
                                                    s_edge, t_node, cursor, jc);

    k3_gather<<<N_NODES, 128, 0, stream>>>(m01, jc, base, count, y);
    k4_gemm<<<N_NODES / 32, 256, 0, stream>>>(y, W, out);
}

// Round 4
// 673.174 us; speedup vs baseline: 4.7760x; 1.0503x over previous
//
#include <hip/hip_runtime.h>
#include <math.h>

#define N_NODES 100000
#define N_EDGES 100000
#define NNZT    1600000
#define C       128
#define NBLK_SCAN ((N_NODES + 255) / 256)   // 391

typedef _Float16 half8 __attribute__((ext_vector_type(8)));

// K1: t_node[i] = dot(x_0[i], a_tgt); also emit x0h = (fp16)x0
__global__ __launch_bounds__(128) void k1_node_dot(
    const float* __restrict__ x0, const float* __restrict__ att,
    float* __restrict__ t_node, _Float16* __restrict__ x0h)
{
    int node = blockIdx.x;
    int tid  = threadIdx.x;
    float x = x0[(size_t)node * C + tid];
    x0h[(size_t)node * C + tid] = (_Float16)x;
    float v = x * att[C + tid];
    #pragma unroll
    for (int off = 32; off > 0; off >>= 1) v += __shfl_down(v, off, 64);
    __shared__ float w0, w1;
    if (tid == 0)  w0 = v;
    if (tid == 64) w1 = v;
    __syncthreads();
    if (tid == 0) t_node[node] = w0 + w1;
}

// K2: segment sum over sorted edge_idx -> m01h row (fp16) + s_edge dot.
// 128 thr = 8 edge-slots x 16 lanes x 16B(half8); 2x unroll -> 16 rows in flight.
__global__ __launch_bounds__(128) void k2_edge_msg(
    const half8* __restrict__ x0h,
    const int*   __restrict__ node_idx,
    const int*   __restrict__ edge_idx,
    const float* __restrict__ values,
    const float* __restrict__ att,
    half8* __restrict__ m01h,
    float* __restrict__ s_edge)
{
    int j    = blockIdx.x;
    int tid  = threadIdx.x;
    int sub  = tid >> 4;            // 0..7 edge slot
    int lane = tid & 15;            // half8 chunk of the row
    __shared__ int seg[2];
    if (tid == 0) {
        int lo = 0, hi = NNZT;
        while (lo < hi) { int mid = (lo + hi) >> 1; if (edge_idx[mid] <  j) lo = mid + 1; else hi = mid; }
        seg[0] = lo;
        hi = NNZT;
        while (lo < hi) { int mid = (lo + hi) >> 1; if (edge_idx[mid] <= j) lo = mid + 1; else hi = mid; }
        seg[1] = lo;
    }
    __syncthreads();
    int start = seg[0], end = seg[1];

    float facc[8];
    #pragma unroll
    for (int q = 0; q < 8; ++q) facc[q] = 0.f;

    int e = start + sub;
    for (; e + 8 < end; e += 16) {
        int   n0 = node_idx[e];
        int   n1 = node_idx[e + 8];
        float v0 = values[e];
        float v1 = values[e + 8];
        half8 a = x0h[(size_t)n0 * 16 + lane];
        half8 b = x0h[(size_t)n1 * 16 + lane];
        #pragma unroll
        for (int q = 0; q < 8; ++q)
            facc[q] += v0 * (float)a[q] + v1 * (float)b[q];
    }
    if (e < end) {
        int   n0 = node_idx[e];
        float v0 = values[e];
        half8 a = x0h[(size_t)n0 * 16 + lane];
        #pragma unroll
        for (int q = 0; q < 8; ++q) facc[q] += v0 * (float)a[q];
    }

    __shared__ float red[128][8];
    #pragma unroll
    for (int q = 0; q < 8; ++q) red[tid][q] = facc[q];
    __syncthreads();
    if (tid < 16) {
        float s[8];
        #pragma unroll
        for (int q = 0; q < 8; ++q) {
            float t = 0.f;
            #pragma unroll
            for (int ss = 0; ss < 8; ++ss) t += red[ss * 16 + tid][q];
            s[q] = t;
        }
        half8 h;
        #pragma unroll
        for (int q = 0; q < 8; ++q) h[q] = (_Float16)s[q];
        m01h[(size_t)j * 16 + tid] = h;
        const float* attp = att + tid * 8;
        float p = 0.f;
        #pragma unroll
        for (int q = 0; q < 8; ++q) p += s[q] * attp[q];
        #pragma unroll
        for (int off = 8; off > 0; off >>= 1) p += __shfl_down(p, off, 16);
        if (tid == 0) s_edge[j] = p;
    }
}

// H: histogram of node_idx
__global__ __launch_bounds__(256) void k_hist(
    const int* __restrict__ node_idx, int* __restrict__ count)
{
    int e = blockIdx.x * 256 + threadIdx.x;
    if (e < NNZT) atomicAdd(&count[node_idx[e]], 1);
}

// S1: per-256-chunk sums
__global__ __launch_bounds__(256) void k_scan1(
    const int* __restrict__ count, int* __restrict__ bsum)
{
    __shared__ int s[256];
    int tid = threadIdx.x;
    int i = blockIdx.x * 256 + tid;
    s[tid] = (i < N_NODES) ? count[i] : 0;
    __syncthreads();
    #pragma unroll
    for (int off = 128; off > 0; off >>= 1) {
        if (tid < off) s[tid] += s[tid + off];
        __syncthreads();
    }
    if (tid == 0) bsum[blockIdx.x] = s[0];
}

// S2: exclusive scan of block sums (single block, nb <= 512)
__global__ __launch_bounds__(512) void k_scan2(int* __restrict__ bsum)
{
    __shared__ int s[512];
    int tid = threadIdx.x;
    int v = (tid < NBLK_SCAN) ? bsum[tid] : 0;
    s[tid] = v;
    __syncthreads();
    for (int off = 1; off < 512; off <<= 1) {
        int t = (tid >= off) ? s[tid - off] : 0;
        __syncthreads();
        s[tid] += t;
        __syncthreads();
    }
    if (tid < NBLK_SCAN) bsum[tid] = s[tid] - v;   // exclusive
}

// S3: in-chunk exclusive scan + block offset -> base, cursor
__global__ __launch_bounds__(256) void k_scan3(
    const int* __restrict__ count, const int* __restrict__ bsum,
    int* __restrict__ base, int* __restrict__ cursor)
{
    __shared__ int s[256];
    int tid = threadIdx.x;
    int i = blockIdx.x * 256 + tid;
    int v = (i < N_NODES) ? count[i] : 0;
    s[tid] = v;
    __syncthreads();
    for (int off = 1; off < 256; off <<= 1) {
        int t = (tid >= off) ? s[tid - off] : 0;
        __syncthreads();
        s[tid] += t;
        __syncthreads();
    }
    if (i < N_NODES) {
        int excl = s[tid] - v + bsum[blockIdx.x];
        base[i]   = excl;
        cursor[i] = excl;
    }
}

// F: scatter edges into CSR order; coef = elu(s_j + t_n) * v_e packed with j
__global__ __launch_bounds__(256) void k_fill(
    const int*   __restrict__ node_idx,
    const int*   __restrict__ edge_idx,
    const float* __restrict__ values,
    const float* __restrict__ s_edge,
    const float* __restrict__ t_node,
    int*   __restrict__ cursor,
    int2*  __restrict__ jc)
{
    int e = blockIdx.x * 256 + threadIdx.x;
    if (e >= NNZT) return;
    int n = node_idx[e];
    int j = edge_idx[e];
    float s = s_edge[j] + t_node[n];
    float coef = (s > 0.f ? s : expm1f(s)) * values[e];
    int pos = atomicAdd(&cursor[n], 1);
    jc[pos] = make_int2(j, __float_as_int(coef));
}

// K3: gather-accumulate per destination node (atomic-free), fp16 rows,
// 16 rows in flight per block
__global__ __launch_bounds__(128) void k3_gather(
    const half8* __restrict__ m01h,
    const int2*  __restrict__ jc,
    const int*   __restrict__ base,
    const int*   __restrict__ count,
    float* __restrict__ y)
{
    int n    = blockIdx.x;
    int tid  = threadIdx.x;
    int sub  = tid >> 4;
    int lane = tid & 15;
    int b    = base[n];
    int cnt  = count[n];

    float facc[8];
    #pragma unroll
    for (int q = 0; q < 8; ++q) facc[q] = 0.f;

    int i = sub;
    for (; i + 8 < cnt; i += 16) {
        int2 p0 = jc[b + i];
        int2 p1 = jc[b + i + 8];
        float c0 = __int_as_float(p0.y);
        float c1 = __int_as_float(p1.y);
        half8 a = m01h[(size_t)p0.x * 16 + lane];
        half8 bb = m01h[(size_t)p1.x * 16 + lane];
        #pragma unroll
        for (int q = 0; q < 8; ++q)
            facc[q] += c0 * (float)a[q] + c1 * (float)bb[q];
    }
    if (i < cnt) {
        int2 p0 = jc[b + i];
        float c0 = __int_as_float(p0.y);
        half8 a = m01h[(size_t)p0.x * 16 + lane];
        #pragma unroll
        for (int q = 0; q < 8; ++q) facc[q] += c0 * (float)a[q];
    }

    __shared__ float red[128][8];
    #pragma unroll
    for (int q = 0; q < 8; ++q) red[tid][q] = facc[q];
    __syncthreads();
    if (tid < 16) {
        float s[8];
        #pragma unroll
        for (int q = 0; q < 8; ++q) {
            float t = 0.f;
            #pragma unroll
            for (int ss = 0; ss < 8; ++ss) t += red[ss * 16 + tid][q];
            s[q] = t;
        }
        float* yr = y + (size_t)n * C + tid * 8;
        *reinterpret_cast<float4*>(yr)     = make_float4(s[0], s[1], s[2], s[3]);
        *reinterpret_cast<float4*>(yr + 4) = make_float4(s[4], s[5], s[6], s[7]);
    }
}

// K4: out = y @ W
__global__ __launch_bounds__(256) void k4_gemm(
    const float* __restrict__ y,
    const float* __restrict__ W,
    float* __restrict__ out)
{
    __shared__ float Wl[C * C];
    __shared__ float yl[32 * C];
    int tid = threadIdx.x;
    int rowbase = blockIdx.x * 32;
    for (int i = tid; i < C * C / 4; i += 256)
        reinterpret_cast<float4*>(Wl)[i] = reinterpret_cast<const float4*>(W)[i];
    for (int i = tid; i < 32 * C / 4; i += 256) {
        int r = i >> 5;
        reinterpret_cast<float4*>(yl)[i] =
            reinterpret_cast<const float4*>(y + (size_t)(rowbase + r) * C)[i & 31];
    }
    __syncthreads();
    int r8 = tid >> 5;
    int cg = (tid & 31) << 2;
    float4 acc[4];
    #pragma unroll
    for (int rr = 0; rr < 4; ++rr) acc[rr] = make_float4(0.f, 0.f, 0.f, 0.f);
    for (int k = 0; k < C; ++k) {
        float4 w4 = *reinterpret_cast<const float4*>(&Wl[k * C + cg]);
        #pragma unroll
        for (int rr = 0; rr < 4; ++rr) {
            float yv = yl[(r8 + rr * 8) * C + k];
            acc[rr].x += yv * w4.x;
            acc[rr].y += yv * w4.y;
            acc[rr].z += yv * w4.z;
            acc[rr].w += yv * w4.w;
        }
    }
    #pragma unroll
    for (int rr = 0; rr < 4; ++rr) {
        int r = rowbase + r8 + rr * 8;
        *reinterpret_cast<float4*>(&out[(size_t)r * C + cg]) = acc[rr];
    }
}

extern "C" void kernel_launch(void* const* d_in, const int* in_sizes, int n_in,
                              void* d_out, int out_size, void* d_ws, size_t ws_size,
                              hipStream_t stream)
{
    const float* x0       = (const float*)d_in[0];
    const int*   node_idx = (const int*)  d_in[1];
    const int*   edge_idx = (const int*)  d_in[2];
    const float* values   = (const float*)d_in[3];
    const float* W        = (const float*)d_in[4];
    const float* att      = (const float*)d_in[5];
    float* out = (float*)d_out;

    // fp16 gather tables live in d_out (2 x 25.6 MB = exactly out_size bytes);
    // both are dead before k4 overwrites d_out with the final output.
    _Float16* x0h_s  = (_Float16*)d_out;
    _Float16* m01h_s = x0h_s + (size_t)N_NODES * C;

    char*  p   = (char*)d_ws;
    float* y      = (float*)p;  p += (size_t)N_NODES * C * sizeof(float); // 51.2 MB
    float* t_node = (float*)p;  p += N_NODES * sizeof(float);
    float* s_edge = (float*)p;  p += N_EDGES * sizeof(float);
    int*   count  = (int*)p;    p += N_NODES * sizeof(int);
    int*   base   = (int*)p;    p += N_NODES * sizeof(int);
    int*   cursor = (int*)p;    p += N_NODES * sizeof(int);
    int*   bsum   = (int*)p;    p += 512 * sizeof(int);
    int2*  jc     = (int2*)p;   p += (size_t)NNZT * sizeof(int2);         // 12.8 MB

    hipMemsetAsync(count, 0, N_NODES * sizeof(int), stream);

    k1_node_dot<<<N_NODES, 128, 0, stream>>>(x0, att, t_node, x0h_s);
    k2_edge_msg<<<N_EDGES, 128, 0, stream>>>((const half8*)x0h_s, node_idx, edge_idx,
                                             values, att, (half8*)m01h_s, s_edge);

    k_hist <<<(NNZT + 255) / 256, 256, 0, stream>>>(node_idx, count);
    k_scan1<<<NBLK_SCAN, 256, 0, stream>>>(count, bsum);
    k_scan2<<<1, 512, 0, stream>>>(bsum);
    k_scan3<<<NBLK_SCAN, 256, 0, stream>>>(count, bsum, base, cursor);
    k_fill <<<(NNZT + 255) / 256, 256, 0, stream>>>(node_idx, edge_idx, values,
                                                    s_edge, t_node, cursor, jc);

    k3_gather<<<N_NODES, 128, 0, stream>>>((const half8*)m01h_s, jc, base, count, y);
    k4_gemm<<<N_NODES / 32, 256, 0, stream>>>(y, W, out);
}

// Round 5
// 536.077 us; speedup vs baseline: 5.9975x; 1.2557x over previous
//
#include <hip/hip_runtime.h>
#include <math.h>

#define N_NODES 100000
#define N_EDGES 100000
#define NNZT    1600000
#define C       128
#define NBLK_SCAN ((N_NODES + 255) / 256)   // 391

typedef _Float16 half8 __attribute__((ext_vector_type(8)));

// K1: t_node[i] = dot(x_0[i], a_tgt); also emit x0h = (fp16)x0
__global__ __launch_bounds__(128) void k1_node_dot(
    const float* __restrict__ x0, const float* __restrict__ att,
    float* __restrict__ t_node, _Float16* __restrict__ x0h)
{
    int node = blockIdx.x;
    int tid  = threadIdx.x;
    float x = x0[(size_t)node * C + tid];
    x0h[(size_t)node * C + tid] = (_Float16)x;
    float v = x * att[C + tid];
    #pragma unroll
    for (int off = 32; off > 0; off >>= 1) v += __shfl_down(v, off, 64);
    __shared__ float w0, w1;
    if (tid == 0)  w0 = v;
    if (tid == 64) w1 = v;
    __syncthreads();
    if (tid == 0) t_node[node] = w0 + w1;
}

// RP: edge row pointer from sorted edge_idx, atomic-free one pass.
// row_start[j] = lower_bound(edge_idx, j); row_start[N_EDGES] = NNZT.
__global__ __launch_bounds__(256) void k_rowptr(
    const int* __restrict__ edge_idx, int* __restrict__ row_start)
{
    int e = blockIdx.x * 256 + threadIdx.x;
    if (e >= NNZT) return;
    int j = edge_idx[e];
    int jprev = (e == 0) ? -1 : edge_idx[e - 1];
    for (int k = jprev + 1; k <= j; ++k) row_start[k] = e;
    if (e == NNZT - 1)
        for (int k = j + 1; k <= N_EDGES; ++k) row_start[k] = NNZT;
}

// K2: segment sum -> m01h row (fp16) + s_edge dot. No binary search:
// start/end from precomputed row_start (scalar loads).
// 128 thr = 8 edge-slots x 16 lanes x 16B(half8); 2x unroll -> 16 rows in flight.
__global__ __launch_bounds__(128) void k2_edge_msg(
    const half8* __restrict__ x0h,
    const int*   __restrict__ node_idx,
    const int*   __restrict__ row_start,
    const float* __restrict__ values,
    const float* __restrict__ att,
    half8* __restrict__ m01h,
    float* __restrict__ s_edge)
{
    int j    = blockIdx.x;
    int tid  = threadIdx.x;
    int sub  = tid >> 4;            // 0..7 edge slot
    int lane = tid & 15;            // half8 chunk of the row
    int start = row_start[j];
    int end   = row_start[j + 1];

    float facc[8];
    #pragma unroll
    for (int q = 0; q < 8; ++q) facc[q] = 0.f;

    int e = start + sub;
    for (; e + 8 < end; e += 16) {
        int   n0 = node_idx[e];
        int   n1 = node_idx[e + 8];
        float v0 = values[e];
        float v1 = values[e + 8];
        half8 a = x0h[(size_t)n0 * 16 + lane];
        half8 b = x0h[(size_t)n1 * 16 + lane];
        #pragma unroll
        for (int q = 0; q < 8; ++q)
            facc[q] += v0 * (float)a[q] + v1 * (float)b[q];
    }
    if (e < end) {
        int   n0 = node_idx[e];
        float v0 = values[e];
        half8 a = x0h[(size_t)n0 * 16 + lane];
        #pragma unroll
        for (int q = 0; q < 8; ++q) facc[q] += v0 * (float)a[q];
    }

    __shared__ float red[128][9];   // +1 pad: stride-9 -> conflict-free reduce
    #pragma unroll
    for (int q = 0; q < 8; ++q) red[tid][q] = facc[q];
    __syncthreads();
    if (tid < 16) {
        float s[8];
        #pragma unroll
        for (int q = 0; q < 8; ++q) {
            float t = 0.f;
            #pragma unroll
            for (int ss = 0; ss < 8; ++ss) t += red[ss * 16 + tid][q];
            s[q] = t;
        }
        half8 h;
        #pragma unroll
        for (int q = 0; q < 8; ++q) h[q] = (_Float16)s[q];
        m01h[(size_t)j * 16 + tid] = h;
        const float* attp = att + tid * 8;
        float p = 0.f;
        #pragma unroll
        for (int q = 0; q < 8; ++q) p += s[q] * attp[q];
        #pragma unroll
        for (int off = 8; off > 0; off >>= 1) p += __shfl_down(p, off, 16);
        if (tid == 0) s_edge[j] = p;
    }
}

// H: histogram of node_idx
__global__ __launch_bounds__(256) void k_hist(
    const int* __restrict__ node_idx, int* __restrict__ count)
{
    int e = blockIdx.x * 256 + threadIdx.x;
    if (e < NNZT) atomicAdd(&count[node_idx[e]], 1);
}

// S1: per-256-chunk sums
__global__ __launch_bounds__(256) void k_scan1(
    const int* __restrict__ count, int* __restrict__ bsum)
{
    __shared__ int s[256];
    int tid = threadIdx.x;
    int i = blockIdx.x * 256 + tid;
    s[tid] = (i < N_NODES) ? count[i] : 0;
    __syncthreads();
    #pragma unroll
    for (int off = 128; off > 0; off >>= 1) {
        if (tid < off) s[tid] += s[tid + off];
        __syncthreads();
    }
    if (tid == 0) bsum[blockIdx.x] = s[0];
}

// S2: exclusive scan of block sums (single block, nb <= 512)
__global__ __launch_bounds__(512) void k_scan2(int* __restrict__ bsum)
{
    __shared__ int s[512];
    int tid = threadIdx.x;
    int v = (tid < NBLK_SCAN) ? bsum[tid] : 0;
    s[tid] = v;
    __syncthreads();
    for (int off = 1; off < 512; off <<= 1) {
        int t = (tid >= off) ? s[tid - off] : 0;
        __syncthreads();
        s[tid] += t;
        __syncthreads();
    }
    if (tid < NBLK_SCAN) bsum[tid] = s[tid] - v;   // exclusive
}

// S3: in-chunk exclusive scan + block offset -> base, cursor
__global__ __launch_bounds__(256) void k_scan3(
    const int* __restrict__ count, const int* __restrict__ bsum,
    int* __restrict__ base, int* __restrict__ cursor)
{
    __shared__ int s[256];
    int tid = threadIdx.x;
    int i = blockIdx.x * 256 + tid;
    int v = (i < N_NODES) ? count[i] : 0;
    s[tid] = v;
    __syncthreads();
    for (int off = 1; off < 256; off <<= 1) {
        int t = (tid >= off) ? s[tid - off] : 0;
        __syncthreads();
        s[tid] += t;
        __syncthreads();
    }
    if (i < N_NODES) {
        int excl = s[tid] - v + bsum[blockIdx.x];
        base[i]   = excl;
        cursor[i] = excl;
    }
}

// F: scatter edges into CSR order; coef = elu(s_j + t_n) * v_e packed with j
__global__ __launch_bounds__(256) void k_fill(
    const int*   __restrict__ node_idx,
    const int*   __restrict__ edge_idx,
    const float* __restrict__ values,
    const float* __restrict__ s_edge,
    const float* __restrict__ t_node,
    int*   __restrict__ cursor,
    int2*  __restrict__ jc)
{
    int e = blockIdx.x * 256 + threadIdx.x;
    if (e >= NNZT) return;
    int n = node_idx[e];
    int j = edge_idx[e];
    float s = s_edge[j] + t_node[n];
    float coef = (s > 0.f ? s : expm1f(s)) * values[e];
    int pos = atomicAdd(&cursor[n], 1);
    jc[pos] = make_int2(j, __float_as_int(coef));
}

// K3: gather-accumulate per destination node (atomic-free), fp16 rows,
// 16 rows in flight per block
__global__ __launch_bounds__(128) void k3_gather(
    const half8* __restrict__ m01h,
    const int2*  __restrict__ jc,
    const int*   __restrict__ base,
    const int*   __restrict__ count,
    float* __restrict__ y)
{
    int n    = blockIdx.x;
    int tid  = threadIdx.x;
    int sub  = tid >> 4;
    int lane = tid & 15;
    int b    = base[n];
    int cnt  = count[n];

    float facc[8];
    #pragma unroll
    for (int q = 0; q < 8; ++q) facc[q] = 0.f;

    int i = sub;
    for (; i + 8 < cnt; i += 16) {
        int2 p0 = jc[b + i];
        int2 p1 = jc[b + i + 8];
        float c0 = __int_as_float(p0.y);
        float c1 = __int_as_float(p1.y);
        half8 a = m01h[(size_t)p0.x * 16 + lane];
        half8 bb = m01h[(size_t)p1.x * 16 + lane];
        #pragma unroll
        for (int q = 0; q < 8; ++q)
            facc[q] += c0 * (float)a[q] + c1 * (float)bb[q];
    }
    if (i < cnt) {
        int2 p0 = jc[b + i];
        float c0 = __int_as_float(p0.y);
        half8 a = m01h[(size_t)p0.x * 16 + lane];
        #pragma unroll
        for (int q = 0; q < 8; ++q) facc[q] += c0 * (float)a[q];
    }

    __shared__ float red[128][9];   // +1 pad: conflict-free reduce
    #pragma unroll
    for (int q = 0; q < 8; ++q) red[tid][q] = facc[q];
    __syncthreads();
    if (tid < 16) {
        float s[8];
        #pragma unroll
        for (int q = 0; q < 8; ++q) {
            float t = 0.f;
            #pragma unroll
            for (int ss = 0; ss < 8; ++ss) t += red[ss * 16 + tid][q];
            s[q] = t;
        }
        float* yr = y + (size_t)n * C + tid * 8;
        *reinterpret_cast<float4*>(yr)     = make_float4(s[0], s[1], s[2], s[3]);
        *reinterpret_cast<float4*>(yr + 4) = make_float4(s[4], s[5], s[6], s[7]);
    }
}

// K4: out = y @ W
__global__ __launch_bounds__(256) void k4_gemm(
    const float* __restrict__ y,
    const float* __restrict__ W,
    float* __restrict__ out)
{
    __shared__ float Wl[C * C];
    __shared__ float yl[32 * C];
    int tid = threadIdx.x;
    int rowbase = blockIdx.x * 32;
    for (int i = tid; i < C * C / 4; i += 256)
        reinterpret_cast<float4*>(Wl)[i] = reinterpret_cast<const float4*>(W)[i];
    for (int i = tid; i < 32 * C / 4; i += 256) {
        int r = i >> 5;
        reinterpret_cast<float4*>(yl)[i] =
            reinterpret_cast<const float4*>(y + (size_t)(rowbase + r) * C)[i & 31];
    }
    __syncthreads();
    int r8 = tid >> 5;
    int cg = (tid & 31) << 2;
    float4 acc[4];
    #pragma unroll
    for (int rr = 0; rr < 4; ++rr) acc[rr] = make_float4(0.f, 0.f, 0.f, 0.f);
    for (int k = 0; k < C; ++k) {
        float4 w4 = *reinterpret_cast<const float4*>(&Wl[k * C + cg]);
        #pragma unroll
        for (int rr = 0; rr < 4; ++rr) {
            float yv = yl[(r8 + rr * 8) * C + k];
            acc[rr].x += yv * w4.x;
            acc[rr].y += yv * w4.y;
            acc[rr].z += yv * w4.z;
            acc[rr].w += yv * w4.w;
        }
    }
    #pragma unroll
    for (int rr = 0; rr < 4; ++rr) {
        int r = rowbase + r8 + rr * 8;
        *reinterpret_cast<float4*>(&out[(size_t)r * C + cg]) = acc[rr];
    }
}

extern "C" void kernel_launch(void* const* d_in, const int* in_sizes, int n_in,
                              void* d_out, int out_size, void* d_ws, size_t ws_size,
                              hipStream_t stream)
{
    const float* x0       = (const float*)d_in[0];
    const int*   node_idx = (const int*)  d_in[1];
    const int*   edge_idx = (const int*)  d_in[2];
    const float* values   = (const float*)d_in[3];
    const float* W        = (const float*)d_in[4];
    const float* att      = (const float*)d_in[5];
    float* out = (float*)d_out;

    // fp16 gather tables live in d_out (2 x 25.6 MB = exactly out_size bytes);
    // both are dead before k4 overwrites d_out with the final output.
    _Float16* x0h_s  = (_Float16*)d_out;
    _Float16* m01h_s = x0h_s + (size_t)N_NODES * C;

    char*  p   = (char*)d_ws;
    float* y        = (float*)p;  p += (size_t)N_NODES * C * sizeof(float); // 51.2 MB
    float* t_node   = (float*)p;  p += N_NODES * sizeof(float);
    float* s_edge   = (float*)p;  p += N_EDGES * sizeof(float);
    int*   count    = (int*)p;    p += N_NODES * sizeof(int);
    int*   base     = (int*)p;    p += N_NODES * sizeof(int);
    int*   cursor   = (int*)p;    p += N_NODES * sizeof(int);
    int*   bsum     = (int*)p;    p += 512 * sizeof(int);
    int*   row_start= (int*)p;    p += (N_EDGES + 1) * sizeof(int);
    int2*  jc       = (int2*)p;   p += (size_t)NNZT * sizeof(int2);         // 12.8 MB

    hipMemsetAsync(count, 0, N_NODES * sizeof(int), stream);

    k1_node_dot<<<N_NODES, 128, 0, stream>>>(x0, att, t_node, x0h_s);
    k_rowptr<<<(NNZT + 255) / 256, 256, 0, stream>>>(edge_idx, row_start);
    k2_edge_msg<<<N_EDGES, 128, 0, stream>>>((const half8*)x0h_s, node_idx, row_start,
                                             values, att, (half8*)m01h_s, s_edge);

    k_hist <<<(NNZT + 255) / 256, 256, 0, stream>>>(node_idx, count);
    k_scan1<<<NBLK_SCAN, 256, 0, stream>>>(count, bsum);
    k_scan2<<<1, 512, 0, stream>>>(bsum);
    k_scan3<<<NBLK_SCAN, 256, 0, stream>>>(count, bsum, base, cursor);
    k_fill <<<(NNZT + 255) / 256, 256, 0, stream>>>(node_idx, edge_idx, values,
                                                    s_edge, t_node, cursor, jc);

    k3_gather<<<N_NODES, 128, 0, stream>>>((const half8*)m01h_s, jc, base, count, y);
    k4_gemm<<<N_NODES / 32, 256, 0, stream>>>(y, W, out);
}

// Round 6
// 483.121 us; speedup vs baseline: 6.6548x; 1.1096x over previous
//
#include <hip/hip_runtime.h>
#include <math.h>

#define N_NODES 100000
#define N_EDGES 100000
#define NNZT    1600000
#define C       128
#define NBLK_SCAN ((N_NODES + 255) / 256)   // 391
#define NB        ((N_NODES + 255) >> 8)    // 391 node-buckets of 256 nodes
#define EPB       8192                      // edges per binA block

typedef _Float16 half8 __attribute__((ext_vector_type(8)));

// K1: t_node[i] = dot(x_0[i], a_tgt); also emit x0h = (fp16)x0
__global__ __launch_bounds__(128) void k1_node_dot(
    const float* __restrict__ x0, const float* __restrict__ att,
    float* __restrict__ t_node, _Float16* __restrict__ x0h)
{
    int node = blockIdx.x;
    int tid  = threadIdx.x;
    float x = x0[(size_t)node * C + tid];
    x0h[(size_t)node * C + tid] = (_Float16)x;
    float v = x * att[C + tid];
    #pragma unroll
    for (int off = 32; off > 0; off >>= 1) v += __shfl_down(v, off, 64);
    __shared__ float w0, w1;
    if (tid == 0)  w0 = v;
    if (tid == 64) w1 = v;
    __syncthreads();
    if (tid == 0) t_node[node] = w0 + w1;
}

// RP: edge row pointer from sorted edge_idx, atomic-free one pass.
__global__ __launch_bounds__(256) void k_rowptr(
    const int* __restrict__ edge_idx, int* __restrict__ row_start)
{
    int e = blockIdx.x * 256 + threadIdx.x;
    if (e >= NNZT) return;
    int j = edge_idx[e];
    int jprev = (e == 0) ? -1 : edge_idx[e - 1];
    for (int k = jprev + 1; k <= j; ++k) row_start[k] = e;
    if (e == NNZT - 1)
        for (int k = j + 1; k <= N_EDGES; ++k) row_start[k] = NNZT;
}

// K2: segment sum -> m01h row (fp16) + s_edge dot, via row_start.
__global__ __launch_bounds__(128) void k2_edge_msg(
    const half8* __restrict__ x0h,
    const int*   __restrict__ node_idx,
    const int*   __restrict__ row_start,
    const float* __restrict__ values,
    const float* __restrict__ att,
    half8* __restrict__ m01h,
    float* __restrict__ s_edge)
{
    int j    = blockIdx.x;
    int tid  = threadIdx.x;
    int sub  = tid >> 4;            // 0..7 edge slot
    int lane = tid & 15;            // half8 chunk of the row
    int start = row_start[j];
    int end   = row_start[j + 1];

    float facc[8];
    #pragma unroll
    for (int q = 0; q < 8; ++q) facc[q] = 0.f;

    int e = start + sub;
    for (; e + 8 < end; e += 16) {
        int   n0 = node_idx[e];
        int   n1 = node_idx[e + 8];
        float v0 = values[e];
        float v1 = values[e + 8];
        half8 a = x0h[(size_t)n0 * 16 + lane];
        half8 b = x0h[(size_t)n1 * 16 + lane];
        #pragma unroll
        for (int q = 0; q < 8; ++q)
            facc[q] += v0 * (float)a[q] + v1 * (float)b[q];
    }
    if (e < end) {
        int   n0 = node_idx[e];
        float v0 = values[e];
        half8 a = x0h[(size_t)n0 * 16 + lane];
        #pragma unroll
        for (int q = 0; q < 8; ++q) facc[q] += v0 * (float)a[q];
    }

    __shared__ float red[128][9];   // +1 pad: conflict-free reduce
    #pragma unroll
    for (int q = 0; q < 8; ++q) red[tid][q] = facc[q];
    __syncthreads();
    if (tid < 16) {
        float s[8];
        #pragma unroll
        for (int q = 0; q < 8; ++q) {
            float t = 0.f;
            #pragma unroll
            for (int ss = 0; ss < 8; ++ss) t += red[ss * 16 + tid][q];
            s[q] = t;
        }
        half8 h;
        #pragma unroll
        for (int q = 0; q < 8; ++q) h[q] = (_Float16)s[q];
        m01h[(size_t)j * 16 + tid] = h;
        const float* attp = att + tid * 8;
        float p = 0.f;
        #pragma unroll
        for (int q = 0; q < 8; ++q) p += s[q] * attp[q];
        #pragma unroll
        for (int off = 8; off > 0; off >>= 1) p += __shfl_down(p, off, 16);
        if (tid == 0) s_edge[j] = p;
    }
}

// H: histogram of node_idx
__global__ __launch_bounds__(256) void k_hist(
    const int* __restrict__ node_idx, int* __restrict__ count)
{
    int e = blockIdx.x * 256 + threadIdx.x;
    if (e < NNZT) atomicAdd(&count[node_idx[e]], 1);
}

// S1: per-256-chunk sums
__global__ __launch_bounds__(256) void k_scan1(
    const int* __restrict__ count, int* __restrict__ bsum)
{
    __shared__ int s[256];
    int tid = threadIdx.x;
    int i = blockIdx.x * 256 + tid;
    s[tid] = (i < N_NODES) ? count[i] : 0;
    __syncthreads();
    #pragma unroll
    for (int off = 128; off > 0; off >>= 1) {
        if (tid < off) s[tid] += s[tid + off];
        __syncthreads();
    }
    if (tid == 0) bsum[blockIdx.x] = s[0];
}

// S2: exclusive scan of block sums
__global__ __launch_bounds__(512) void k_scan2(int* __restrict__ bsum)
{
    __shared__ int s[512];
    int tid = threadIdx.x;
    int v = (tid < NBLK_SCAN) ? bsum[tid] : 0;
    s[tid] = v;
    __syncthreads();
    for (int off = 1; off < 512; off <<= 1) {
        int t = (tid >= off) ? s[tid - off] : 0;
        __syncthreads();
        s[tid] += t;
        __syncthreads();
    }
    if (tid < NBLK_SCAN) bsum[tid] = s[tid] - v;   // exclusive
}

// S3: in-chunk exclusive scan + block offset -> base
__global__ __launch_bounds__(256) void k_scan3(
    const int* __restrict__ count, const int* __restrict__ bsum,
    int* __restrict__ base)
{
    __shared__ int s[256];
    int tid = threadIdx.x;
    int i = blockIdx.x * 256 + tid;
    int v = (i < N_NODES) ? count[i] : 0;
    s[tid] = v;
    __syncthreads();
    for (int off = 1; off < 256; off <<= 1) {
        int t = (tid >= off) ? s[tid - off] : 0;
        __syncthreads();
        s[tid] += t;
        __syncthreads();
    }
    if (i < N_NODES) base[i] = s[tid] - v + bsum[blockIdx.x];
}

// BC: init per-bucket global cursor = bucket base
__global__ __launch_bounds__(256) void k_bcur(
    const int* __restrict__ base, int* __restrict__ bcur)
{
    int b = blockIdx.x * 256 + threadIdx.x;
    if (b < NB) bcur[b] = base[b << 8];
}

// BinA: chunk-reserve scatter into bucket-ordered tmp arrays.
// Each block: LDS bucket histogram over EPB edges, reserve contiguous chunks
// per bucket (1 global atomic/bucket/block), then chunked writes.
__global__ __launch_bounds__(256) void k_binA(
    const int*   __restrict__ node_idx,
    const int*   __restrict__ edge_idx,
    const float* __restrict__ values,
    const float* __restrict__ s_edge,
    const float* __restrict__ t_node,
    int*  __restrict__ bcur,
    int*  __restrict__ tmp_n,
    int2* __restrict__ tmp_jc)
{
    __shared__ int nbuf[EPB];          // 32 KB: staged node ids
    __shared__ int cnt[NB], res[NB];
    int tid = threadIdx.x;
    for (int b = tid; b < NB; b += 256) cnt[b] = 0;
    __syncthreads();
    int e0 = blockIdx.x * EPB;
    for (int i = tid; i < EPB; i += 256) {
        int e = e0 + i;
        if (e < NNZT) {
            int n = node_idx[e];
            nbuf[i] = n;
            atomicAdd(&cnt[n >> 8], 1);
        }
    }
    __syncthreads();
    for (int b = tid; b < NB; b += 256) {
        int c = cnt[b];
        if (c) res[b] = atomicAdd(&bcur[b], c);
        cnt[b] = 0;
    }
    __syncthreads();
    for (int i = tid; i < EPB; i += 256) {
        int e = e0 + i;
        if (e < NNZT) {
            int n = nbuf[i];
            int b = n >> 8;
            int r = atomicAdd(&cnt[b], 1);
            int pos = res[b] + r;
            int j = edge_idx[e];
            float s = s_edge[j] + t_node[n];
            float coef = (s > 0.f ? s : expm1f(s)) * values[e];
            tmp_n[pos]  = n;
            tmp_jc[pos] = make_int2(j, __float_as_int(coef));
        }
    }
}

// BinB: one block per bucket; scatter bucket edges to exact per-node slots
// via LDS cursors. All writes confined to the bucket's ~32 KB jc window.
__global__ __launch_bounds__(256) void k_binB(
    const int*  __restrict__ tmp_n,
    const int2* __restrict__ tmp_jc,
    const int*  __restrict__ base,
    int2* __restrict__ jc)
{
    int b   = blockIdx.x;
    int tid = threadIdx.x;
    int n0  = b << 8;
    __shared__ int cur[256];
    __shared__ int lo_s, hi_s;
    int nn = n0 + tid;
    cur[tid] = (nn < N_NODES) ? base[nn] : 0;
    if (tid == 0) {
        lo_s = base[n0];
        int n1 = n0 + 256;
        hi_s = (n1 < N_NODES) ? base[n1] : NNZT;
    }
    __syncthreads();
    for (int i = lo_s + tid; i < hi_s; i += 256) {
        int n = tmp_n[i];
        int pos = atomicAdd(&cur[n - n0], 1);
        jc[pos] = tmp_jc[i];
    }
}

// K3: gather-accumulate per destination node (atomic-free), fp16 rows
__global__ __launch_bounds__(128) void k3_gather(
    const half8* __restrict__ m01h,
    const int2*  __restrict__ jc,
    const int*   __restrict__ base,
    const int*   __restrict__ count,
    float* __restrict__ y)
{
    int n    = blockIdx.x;
    int tid  = threadIdx.x;
    int sub  = tid >> 4;
    int lane = tid & 15;
    int b    = base[n];
    int cnt  = count[n];

    float facc[8];
    #pragma unroll
    for (int q = 0; q < 8; ++q) facc[q] = 0.f;

    int i = sub;
    for (; i + 8 < cnt; i += 16) {
        int2 p0 = jc[b + i];
        int2 p1 = jc[b + i + 8];
        float c0 = __int_as_float(p0.y);
        float c1 = __int_as_float(p1.y);
        half8 a = m01h[(size_t)p0.x * 16 + lane];
        half8 bb = m01h[(size_t)p1.x * 16 + lane];
        #pragma unroll
        for (int q = 0; q < 8; ++q)
            facc[q] += c0 * (float)a[q] + c1 * (float)bb[q];
    }
    if (i < cnt) {
        int2 p0 = jc[b + i];
        float c0 = __int_as_float(p0.y);
        half8 a = m01h[(size_t)p0.x * 16 + lane];
        #pragma unroll
        for (int q = 0; q < 8; ++q) facc[q] += c0 * (float)a[q];
    }

    __shared__ float red[128][9];
    #pragma unroll
    for (int q = 0; q < 8; ++q) red[tid][q] = facc[q];
    __syncthreads();
    if (tid < 16) {
        float s[8];
        #pragma unroll
        for (int q = 0; q < 8; ++q) {
            float t = 0.f;
            #pragma unroll
            for (int ss = 0; ss < 8; ++ss) t += red[ss * 16 + tid][q];
            s[q] = t;
        }
        float* yr = y + (size_t)n * C + tid * 8;
        *reinterpret_cast<float4*>(yr)     = make_float4(s[0], s[1], s[2], s[3]);
        *reinterpret_cast<float4*>(yr + 4) = make_float4(s[4], s[5], s[6], s[7]);
    }
}

// K4: out = y @ W
__global__ __launch_bounds__(256) void k4_gemm(
    const float* __restrict__ y,
    const float* __restrict__ W,
    float* __restrict__ out)
{
    __shared__ float Wl[C * C];
    __shared__ float yl[32 * C];
    int tid = threadIdx.x;
    int rowbase = blockIdx.x * 32;
    for (int i = tid; i < C * C / 4; i += 256)
        reinterpret_cast<float4*>(Wl)[i] = reinterpret_cast<const float4*>(W)[i];
    for (int i = tid; i < 32 * C / 4; i += 256) {
        int r = i >> 5;
        reinterpret_cast<float4*>(yl)[i] =
            reinterpret_cast<const float4*>(y + (size_t)(rowbase + r) * C)[i & 31];
    }
    __syncthreads();
    int r8 = tid >> 5;
    int cg = (tid & 31) << 2;
    float4 acc[4];
    #pragma unroll
    for (int rr = 0; rr < 4; ++rr) acc[rr] = make_float4(0.f, 0.f, 0.f, 0.f);
    for (int k = 0; k < C; ++k) {
        float4 w4 = *reinterpret_cast<const float4*>(&Wl[k * C + cg]);
        #pragma unroll
        for (int rr = 0; rr < 4; ++rr) {
            float yv = yl[(r8 + rr * 8) * C + k];
            acc[rr].x += yv * w4.x;
            acc[rr].y += yv * w4.y;
            acc[rr].z += yv * w4.z;
            acc[rr].w += yv * w4.w;
        }
    }
    #pragma unroll
    for (int rr = 0; rr < 4; ++rr) {
        int r = rowbase + r8 + rr * 8;
        *reinterpret_cast<float4*>(&out[(size_t)r * C + cg]) = acc[rr];
    }
}

extern "C" void kernel_launch(void* const* d_in, const int* in_sizes, int n_in,
                              void* d_out, int out_size, void* d_ws, size_t ws_size,
                              hipStream_t stream)
{
    const float* x0       = (const float*)d_in[0];
    const int*   node_idx = (const int*)  d_in[1];
    const int*   edge_idx = (const int*)  d_in[2];
    const float* values   = (const float*)d_in[3];
    const float* W        = (const float*)d_in[4];
    const float* att      = (const float*)d_in[5];
    float* out = (float*)d_out;

    // d_out layout: [x0h 25.6MB][m01h 25.6MB]. x0h is dead after k2, so its
    // region is reused for the binning temporaries (19.2 MB <= 25.6 MB).
    // Everything here is dead before k4 writes the final output.
    _Float16* x0h_s  = (_Float16*)d_out;
    _Float16* m01h_s = x0h_s + (size_t)N_NODES * C;
    int*  tmp_n  = (int*)d_out;                               // 6.4 MB
    int2* tmp_jc = (int2*)((char*)d_out + (size_t)NNZT * 4);  // 12.8 MB

    char*  p   = (char*)d_ws;
    float* y        = (float*)p;  p += (size_t)N_NODES * C * sizeof(float); // 51.2 MB
    float* t_node   = (float*)p;  p += N_NODES * sizeof(float);
    float* s_edge   = (float*)p;  p += N_EDGES * sizeof(float);
    int*   count    = (int*)p;    p += N_NODES * sizeof(int);
    int*   base     = (int*)p;    p += N_NODES * sizeof(int);
    int*   bsum     = (int*)p;    p += 512 * sizeof(int);
    int*   bcur     = (int*)p;    p += 512 * sizeof(int);
    int*   row_start= (int*)p;    p += (N_EDGES + 1) * sizeof(int);
    int2*  jc       = (int2*)p;   p += (size_t)NNZT * sizeof(int2);         // 12.8 MB

    hipMemsetAsync(count, 0, N_NODES * sizeof(int), stream);

    k1_node_dot<<<N_NODES, 128, 0, stream>>>(x0, att, t_node, x0h_s);
    k_rowptr<<<(NNZT + 255) / 256, 256, 0, stream>>>(edge_idx, row_start);
    k2_edge_msg<<<N_EDGES, 128, 0, stream>>>((const half8*)x0h_s, node_idx, row_start,
                                             values, att, (half8*)m01h_s, s_edge);

    k_hist <<<(NNZT + 255) / 256, 256, 0, stream>>>(node_idx, count);
    k_scan1<<<NBLK_SCAN, 256, 0, stream>>>(count, bsum);
    k_scan2<<<1, 512, 0, stream>>>(bsum);
    k_scan3<<<NBLK_SCAN, 256, 0, stream>>>(count, bsum, base);
    k_bcur <<<(NB + 255) / 256, 256, 0, stream>>>(base, bcur);

    k_binA<<<(NNZT + EPB - 1) / EPB, 256, 0, stream>>>(node_idx, edge_idx, values,
                                                       s_edge, t_node, bcur, tmp_n, tmp_jc);
    k_binB<<<NB, 256, 0, stream>>>(tmp_n, tmp_jc, base, jc);

    k3_gather<<<N_NODES, 128, 0, stream>>>((const half8*)m01h_s, jc, base, count, y);
    k4_gemm<<<N_NODES / 32, 256, 0, stream>>>(y, W, out);
}

// Round 7
// 458.351 us; speedup vs baseline: 7.0145x; 1.0540x over previous
//
#include <hip/hip_runtime.h>
#include <math.h>

#define N_NODES 100000
#define N_EDGES 100000
#define NNZT    1600000
#define C       128
#define NBLK_SCAN ((N_NODES + 255) / 256)   // 391
#define NB        ((N_NODES + 255) >> 8)    // 391 node-buckets of 256 nodes
#define EPB       8192                      // edges per binA block

typedef _Float16 half8 __attribute__((ext_vector_type(8)));
typedef _Float16 h2    __attribute__((ext_vector_type(2)));
typedef float    f32x4 __attribute__((ext_vector_type(4)));

// K1: t_node[i] = dot(x_0[i], a_tgt); also emit x0h = (fp16)x0
__global__ __launch_bounds__(128) void k1_node_dot(
    const float* __restrict__ x0, const float* __restrict__ att,
    float* __restrict__ t_node, _Float16* __restrict__ x0h)
{
    int node = blockIdx.x;
    int tid  = threadIdx.x;
    float x = x0[(size_t)node * C + tid];
    x0h[(size_t)node * C + tid] = (_Float16)x;
    float v = x * att[C + tid];
    #pragma unroll
    for (int off = 32; off > 0; off >>= 1) v += __shfl_down(v, off, 64);
    __shared__ float w0, w1;
    if (tid == 0)  w0 = v;
    if (tid == 64) w1 = v;
    __syncthreads();
    if (tid == 0) t_node[node] = w0 + w1;
}

// RP: edge row pointer from sorted edge_idx, atomic-free one pass.
__global__ __launch_bounds__(256) void k_rowptr(
    const int* __restrict__ edge_idx, int* __restrict__ row_start)
{
    int e = blockIdx.x * 256 + threadIdx.x;
    if (e >= NNZT) return;
    int j = edge_idx[e];
    int jprev = (e == 0) ? -1 : edge_idx[e - 1];
    for (int k = jprev + 1; k <= j; ++k) row_start[k] = e;
    if (e == NNZT - 1)
        for (int k = j + 1; k <= N_EDGES; ++k) row_start[k] = NNZT;
}

// WC: Wt[n][k] = (fp16) W[k][n]  (transposed fp16 weight for MFMA B-frags)
__global__ __launch_bounds__(256) void k_wcvt(
    const float* __restrict__ W, _Float16* __restrict__ wt)
{
    int i = blockIdx.x * 256 + threadIdx.x;   // 16384
    int k = i >> 7, n = i & 127;
    wt[(size_t)n * C + k] = (_Float16)W[(size_t)k * C + n];
}

// K2: segment sum -> m01h row (fp16) + s_edge dot, via row_start.
// Packed half2 accumulation (v_pk_fma_f16): 4 VALU ops per half8 vs 16.
__global__ __launch_bounds__(128) void k2_edge_msg(
    const half8* __restrict__ x0h,
    const int*   __restrict__ node_idx,
    const int*   __restrict__ row_start,
    const float* __restrict__ values,
    const float* __restrict__ att,
    half8* __restrict__ m01h,
    float* __restrict__ s_edge)
{
    int j    = blockIdx.x;
    int tid  = threadIdx.x;
    int sub  = tid >> 4;            // 0..7 edge slot
    int lane = tid & 15;            // half8 chunk of the row
    int start = row_start[j];
    int end   = row_start[j + 1];

    h2 hacc[4];
    #pragma unroll
    for (int q = 0; q < 4; ++q) hacc[q] = (h2){(_Float16)0.f, (_Float16)0.f};

    int e = start + sub;
    for (; e + 8 < end; e += 16) {
        int   n0 = node_idx[e];
        int   n1 = node_idx[e + 8];
        _Float16 v0 = (_Float16)values[e];
        _Float16 v1 = (_Float16)values[e + 8];
        h2 v0p = {v0, v0}, v1p = {v1, v1};
        half8 A = x0h[(size_t)n0 * 16 + lane];
        half8 B = x0h[(size_t)n1 * 16 + lane];
        const h2* a2 = reinterpret_cast<const h2*>(&A);
        const h2* b2 = reinterpret_cast<const h2*>(&B);
        #pragma unroll
        for (int q = 0; q < 4; ++q)
            hacc[q] = a2[q] * v0p + (b2[q] * v1p + hacc[q]);
    }
    if (e < end) {
        int   n0 = node_idx[e];
        _Float16 v0 = (_Float16)values[e];
        h2 v0p = {v0, v0};
        half8 A = x0h[(size_t)n0 * 16 + lane];
        const h2* a2 = reinterpret_cast<const h2*>(&A);
        #pragma unroll
        for (int q = 0; q < 4; ++q) hacc[q] = a2[q] * v0p + hacc[q];
    }

    __shared__ float red[128][9];   // +1 pad: conflict-free reduce
    #pragma unroll
    for (int q = 0; q < 4; ++q) {
        red[tid][2 * q]     = (float)hacc[q][0];
        red[tid][2 * q + 1] = (float)hacc[q][1];
    }
    __syncthreads();
    if (tid < 16) {
        float s[8];
        #pragma unroll
        for (int q = 0; q < 8; ++q) {
            float t = 0.f;
            #pragma unroll
            for (int ss = 0; ss < 8; ++ss) t += red[ss * 16 + tid][q];
            s[q] = t;
        }
        half8 h;
        #pragma unroll
        for (int q = 0; q < 8; ++q) h[q] = (_Float16)s[q];
        m01h[(size_t)j * 16 + tid] = h;
        const float* attp = att + tid * 8;
        float p = 0.f;
        #pragma unroll
        for (int q = 0; q < 8; ++q) p += s[q] * attp[q];
        #pragma unroll
        for (int off = 8; off > 0; off >>= 1) p += __shfl_down(p, off, 16);
        if (tid == 0) s_edge[j] = p;
    }
}

// H: histogram of node_idx
__global__ __launch_bounds__(256) void k_hist(
    const int* __restrict__ node_idx, int* __restrict__ count)
{
    int e = blockIdx.x * 256 + threadIdx.x;
    if (e < NNZT) atomicAdd(&count[node_idx[e]], 1);
}

// S1: per-256-chunk sums
__global__ __launch_bounds__(256) void k_scan1(
    const int* __restrict__ count, int* __restrict__ bsum)
{
    __shared__ int s[256];
    int tid = threadIdx.x;
    int i = blockIdx.x * 256 + tid;
    s[tid] = (i < N_NODES) ? count[i] : 0;
    __syncthreads();
    #pragma unroll
    for (int off = 128; off > 0; off >>= 1) {
        if (tid < off) s[tid] += s[tid + off];
        __syncthreads();
    }
    if (tid == 0) bsum[blockIdx.x] = s[0];
}

// S2: exclusive scan of block sums
__global__ __launch_bounds__(512) void k_scan2(int* __restrict__ bsum)
{
    __shared__ int s[512];
    int tid = threadIdx.x;
    int v = (tid < NBLK_SCAN) ? bsum[tid] : 0;
    s[tid] = v;
    __syncthreads();
    for (int off = 1; off < 512; off <<= 1) {
        int t = (tid >= off) ? s[tid - off] : 0;
        __syncthreads();
        s[tid] += t;
        __syncthreads();
    }
    if (tid < NBLK_SCAN) bsum[tid] = s[tid] - v;   // exclusive
}

// S3: in-chunk exclusive scan + block offset -> base
__global__ __launch_bounds__(256) void k_scan3(
    const int* __restrict__ count, const int* __restrict__ bsum,
    int* __restrict__ base)
{
    __shared__ int s[256];
    int tid = threadIdx.x;
    int i = blockIdx.x * 256 + tid;
    int v = (i < N_NODES) ? count[i] : 0;
    s[tid] = v;
    __syncthreads();
    for (int off = 1; off < 256; off <<= 1) {
        int t = (tid >= off) ? s[tid - off] : 0;
        __syncthreads();
        s[tid] += t;
        __syncthreads();
    }
    if (i < N_NODES) base[i] = s[tid] - v + bsum[blockIdx.x];
}

// BC: init per-bucket global cursor = bucket base
__global__ __launch_bounds__(256) void k_bcur(
    const int* __restrict__ base, int* __restrict__ bcur)
{
    int b = blockIdx.x * 256 + threadIdx.x;
    if (b < NB) bcur[b] = base[b << 8];
}

// BinA: chunk-reserve scatter into bucket-ordered tmp arrays.
__global__ __launch_bounds__(256) void k_binA(
    const int*   __restrict__ node_idx,
    const int*   __restrict__ edge_idx,
    const float* __restrict__ values,
    const float* __restrict__ s_edge,
    const float* __restrict__ t_node,
    int*  __restrict__ bcur,
    int*  __restrict__ tmp_n,
    int2* __restrict__ tmp_jc)
{
    __shared__ int nbuf[EPB];          // 32 KB: staged node ids
    __shared__ int cnt[NB], res[NB];
    int tid = threadIdx.x;
    for (int b = tid; b < NB; b += 256) cnt[b] = 0;
    __syncthreads();
    int e0 = blockIdx.x * EPB;
    for (int i = tid; i < EPB; i += 256) {
        int e = e0 + i;
        if (e < NNZT) {
            int n = node_idx[e];
            nbuf[i] = n;
            atomicAdd(&cnt[n >> 8], 1);
        }
    }
    __syncthreads();
    for (int b = tid; b < NB; b += 256) {
        int c = cnt[b];
        if (c) res[b] = atomicAdd(&bcur[b], c);
        cnt[b] = 0;
    }
    __syncthreads();
    for (int i = tid; i < EPB; i += 256) {
        int e = e0 + i;
        if (e < NNZT) {
            int n = nbuf[i];
            int b = n >> 8;
            int r = atomicAdd(&cnt[b], 1);
            int pos = res[b] + r;
            int j = edge_idx[e];
            float s = s_edge[j] + t_node[n];
            float coef = (s > 0.f ? s : expm1f(s)) * values[e];
            tmp_n[pos]  = n;
            tmp_jc[pos] = make_int2(j, __float_as_int(coef));
        }
    }
}

// BinB: one block per bucket; scatter to exact per-node slots via LDS cursors.
__global__ __launch_bounds__(256) void k_binB(
    const int*  __restrict__ tmp_n,
    const int2* __restrict__ tmp_jc,
    const int*  __restrict__ base,
    int2* __restrict__ jc)
{
    int b   = blockIdx.x;
    int tid = threadIdx.x;
    int n0  = b << 8;
    __shared__ int cur[256];
    __shared__ int lo_s, hi_s;
    int nn = n0 + tid;
    cur[tid] = (nn < N_NODES) ? base[nn] : 0;
    if (tid == 0) {
        lo_s = base[n0];
        int n1 = n0 + 256;
        hi_s = (n1 < N_NODES) ? base[n1] : NNZT;
    }
    __syncthreads();
    for (int i = lo_s + tid; i < hi_s; i += 256) {
        int n = tmp_n[i];
        int pos = atomicAdd(&cur[n - n0], 1);
        jc[pos] = tmp_jc[i];
    }
}

// K3: gather-accumulate per destination node (atomic-free), fp16 rows;
// emits yh in fp16 for the MFMA GEMM.
__global__ __launch_bounds__(128) void k3_gather(
    const half8* __restrict__ m01h,
    const int2*  __restrict__ jc,
    const int*   __restrict__ base,
    const int*   __restrict__ count,
    _Float16* __restrict__ yh)
{
    int n    = blockIdx.x;
    int tid  = threadIdx.x;
    int sub  = tid >> 4;
    int lane = tid & 15;
    int b    = base[n];
    int cnt  = count[n];

    float facc[8];
    #pragma unroll
    for (int q = 0; q < 8; ++q) facc[q] = 0.f;

    int i = sub;
    for (; i + 8 < cnt; i += 16) {
        int2 p0 = jc[b + i];
        int2 p1 = jc[b + i + 8];
        float c0 = __int_as_float(p0.y);
        float c1 = __int_as_float(p1.y);
        half8 a = m01h[(size_t)p0.x * 16 + lane];
        half8 bb = m01h[(size_t)p1.x * 16 + lane];
        #pragma unroll
        for (int q = 0; q < 8; ++q)
            facc[q] += c0 * (float)a[q] + c1 * (float)bb[q];
    }
    if (i < cnt) {
        int2 p0 = jc[b + i];
        float c0 = __int_as_float(p0.y);
        half8 a = m01h[(size_t)p0.x * 16 + lane];
        #pragma unroll
        for (int q = 0; q < 8; ++q) facc[q] += c0 * (float)a[q];
    }

    __shared__ float red[128][9];
    #pragma unroll
    for (int q = 0; q < 8; ++q) red[tid][q] = facc[q];
    __syncthreads();
    if (tid < 16) {
        half8 h;
        #pragma unroll
        for (int q = 0; q < 8; ++q) {
            float t = 0.f;
            #pragma unroll
            for (int ss = 0; ss < 8; ++ss) t += red[ss * 16 + tid][q];
            h[q] = (_Float16)t;
        }
        *reinterpret_cast<half8*>(yh + (size_t)n * C + tid * 8) = h;
    }
}

// K4: out = yh @ W via MFMA f16. One wave per 16 rows; 8 col-tiles x 4 k-chunks.
// A-frag: A[m=lane&15][k=quad*8+j]; B-frag: B[k=quad*8+j][n=lane&15];
// D: col=lane&15, row=quad*4+reg.
__global__ __launch_bounds__(64) void k4_mfma(
    const _Float16* __restrict__ yh,   // N_NODES x C row-major
    const _Float16* __restrict__ wt,   // wt[n*C+k] = W[k][n]
    float* __restrict__ out)
{
    int lane = threadIdx.x;            // 0..63
    int m    = lane & 15;
    int quad = lane >> 4;              // 0..3
    int rb   = blockIdx.x * 16;        // 6250 blocks x 16 rows = 100000
    const _Float16* yrow = yh + (size_t)(rb + m) * C + quad * 8;
    half8 a[4];
    #pragma unroll
    for (int kc = 0; kc < 4; ++kc)
        a[kc] = *reinterpret_cast<const half8*>(yrow + kc * 32);
    #pragma unroll
    for (int ct = 0; ct < 8; ++ct) {
        const _Float16* wrow = wt + (size_t)(ct * 16 + m) * C + quad * 8;
        f32x4 acc = {0.f, 0.f, 0.f, 0.f};
        #pragma unroll
        for (int kc = 0; kc < 4; ++kc) {
            half8 b = *reinterpret_cast<const half8*>(wrow + kc * 32);
            acc = __builtin_amdgcn_mfma_f32_16x16x32_f16(a[kc], b, acc, 0, 0, 0);
        }
        int orow = rb + quad * 4;
        int ocol = ct * 16 + m;
        #pragma unroll
        for (int r = 0; r < 4; ++r)
            out[(size_t)(orow + r) * C + ocol] = acc[r];
    }
}

extern "C" void kernel_launch(void* const* d_in, const int* in_sizes, int n_in,
                              void* d_out, int out_size, void* d_ws, size_t ws_size,
                              hipStream_t stream)
{
    const float* x0       = (const float*)d_in[0];
    const int*   node_idx = (const int*)  d_in[1];
    const int*   edge_idx = (const int*)  d_in[2];
    const float* values   = (const float*)d_in[3];
    const float* W        = (const float*)d_in[4];
    const float* att      = (const float*)d_in[5];
    float* out = (float*)d_out;

    // d_out layout: [x0h 25.6MB][m01h 25.6MB]. x0h dead after k2 -> reused for
    // binning temporaries (19.2 MB). All dead before k4 writes final output.
    _Float16* x0h_s  = (_Float16*)d_out;
    _Float16* m01h_s = x0h_s + (size_t)N_NODES * C;
    int*  tmp_n  = (int*)d_out;                               // 6.4 MB
    int2* tmp_jc = (int2*)((char*)d_out + (size_t)NNZT * 4);  // 12.8 MB

    char*  p   = (char*)d_ws;
    _Float16* yh    = (_Float16*)p; p += (size_t)N_NODES * C * sizeof(_Float16); // 25.6 MB
    float* t_node   = (float*)p;  p += N_NODES * sizeof(float);
    float* s_edge   = (float*)p;  p += N_EDGES * sizeof(float);
    int*   count    = (int*)p;    p += N_NODES * sizeof(int);
    int*   base     = (int*)p;    p += N_NODES * sizeof(int);
    int*   bsum     = (int*)p;    p += 512 * sizeof(int);
    int*   bcur     = (int*)p;    p += 512 * sizeof(int);
    int*   row_start= (int*)p;    p += (N_EDGES + 1) * sizeof(int);
    _Float16* wt    = (_Float16*)p; p += (size_t)C * C * sizeof(_Float16);       // 32 KB
    int2*  jc       = (int2*)p;   p += (size_t)NNZT * sizeof(int2);              // 12.8 MB

    hipMemsetAsync(count, 0, N_NODES * sizeof(int), stream);

    k1_node_dot<<<N_NODES, 128, 0, stream>>>(x0, att, t_node, x0h_s);
    k_rowptr<<<(NNZT + 255) / 256, 256, 0, stream>>>(edge_idx, row_start);
    k_wcvt  <<<(C * C + 255) / 256, 256, 0, stream>>>(W, wt);
    k2_edge_msg<<<N_EDGES, 128, 0, stream>>>((const half8*)x0h_s, node_idx, row_start,
                                             values, att, (half8*)m01h_s, s_edge);

    k_hist <<<(NNZT + 255) / 256, 256, 0, stream>>>(node_idx, count);
    k_scan1<<<NBLK_SCAN, 256, 0, stream>>>(count, bsum);
    k_scan2<<<1, 512, 0, stream>>>(bsum);
    k_scan3<<<NBLK_SCAN, 256, 0, stream>>>(count, bsum, base);
    k_bcur <<<(NB + 255) / 256, 256, 0, stream>>>(base, bcur);

    k_binA<<<(NNZT + EPB - 1) / EPB, 256, 0, stream>>>(node_idx, edge_idx, values,
                                                       s_edge, t_node, bcur, tmp_n, tmp_jc);
    k_binB<<<NB, 256, 0, stream>>>(tmp_n, tmp_jc, base, jc);

    k3_gather<<<N_NODES, 128, 0, stream>>>((const half8*)m01h_s, jc, base, count, yh);
    k4_mfma<<<N_NODES / 16, 64, 0, stream>>>(yh, wt, out);
}

// Round 8
// 402.796 us; speedup vs baseline: 7.9820x; 1.1379x over previous
//
#include <hip/hip_runtime.h>
#include <math.h>

#define N_NODES 100000
#define N_EDGES 100000
#define NNZT    1600000
#define C       128
#define NB      ((N_NODES + 255) >> 8)    // 391 node-buckets of 256 nodes
#define EPB     8192                      // edges per binA block

typedef _Float16 half8 __attribute__((ext_vector_type(8)));
typedef _Float16 h2    __attribute__((ext_vector_type(2)));
typedef float    f32x4 __attribute__((ext_vector_type(4)));

// K1: t_node[i] = dot(x_0[i], a_tgt); also emit x0h = (fp16)x0
__global__ __launch_bounds__(128) void k1_node_dot(
    const float* __restrict__ x0, const float* __restrict__ att,
    float* __restrict__ t_node, _Float16* __restrict__ x0h)
{
    int node = blockIdx.x;
    int tid  = threadIdx.x;
    float x = x0[(size_t)node * C + tid];
    x0h[(size_t)node * C + tid] = (_Float16)x;
    float v = x * att[C + tid];
    #pragma unroll
    for (int off = 32; off > 0; off >>= 1) v += __shfl_down(v, off, 64);
    __shared__ float w0, w1;
    if (tid == 0)  w0 = v;
    if (tid == 64) w1 = v;
    __syncthreads();
    if (tid == 0) t_node[node] = w0 + w1;
}

// RP: edge row pointer from sorted edge_idx, atomic-free one pass.
__global__ __launch_bounds__(256) void k_rowptr(
    const int* __restrict__ edge_idx, int* __restrict__ row_start)
{
    int e = blockIdx.x * 256 + threadIdx.x;
    if (e >= NNZT) return;
    int j = edge_idx[e];
    int jprev = (e == 0) ? -1 : edge_idx[e - 1];
    for (int k = jprev + 1; k <= j; ++k) row_start[k] = e;
    if (e == NNZT - 1)
        for (int k = j + 1; k <= N_EDGES; ++k) row_start[k] = NNZT;
}

// WC: Wt[n][k] = (fp16) W[k][n]  (transposed fp16 weight for MFMA B-frags)
__global__ __launch_bounds__(256) void k_wcvt(
    const float* __restrict__ W, _Float16* __restrict__ wt)
{
    int i = blockIdx.x * 256 + threadIdx.x;   // 16384
    int k = i >> 7, n = i & 127;
    wt[(size_t)n * C + k] = (_Float16)W[(size_t)k * C + n];
}

// K2: segment sum -> m01h row (fp16) + s_edge dot, via row_start.
// Main loop: 8 edge-slots x 16 lanes x half8. Epilogue: all 128 threads,
// one channel each (conflict-free LDS), coalesced half stores.
__global__ __launch_bounds__(128) void k2_edge_msg(
    const half8* __restrict__ x0h,
    const int*   __restrict__ node_idx,
    const int*   __restrict__ row_start,
    const float* __restrict__ values,
    const float* __restrict__ att,
    _Float16* __restrict__ m01h,
    float* __restrict__ s_edge)
{
    int j    = blockIdx.x;
    int tid  = threadIdx.x;
    int sub  = tid >> 4;            // 0..7 edge slot
    int lane = tid & 15;            // half8 chunk of the row
    int start = row_start[j];
    int end   = row_start[j + 1];

    h2 hacc[4];
    #pragma unroll
    for (int q = 0; q < 4; ++q) hacc[q] = (h2){(_Float16)0.f, (_Float16)0.f};

    int e = start + sub;
    for (; e + 8 < end; e += 16) {
        int   n0 = node_idx[e];
        int   n1 = node_idx[e + 8];
        _Float16 v0 = (_Float16)values[e];
        _Float16 v1 = (_Float16)values[e + 8];
        h2 v0p = {v0, v0}, v1p = {v1, v1};
        half8 A = x0h[(size_t)n0 * 16 + lane];
        half8 B = x0h[(size_t)n1 * 16 + lane];
        const h2* a2 = reinterpret_cast<const h2*>(&A);
        const h2* b2 = reinterpret_cast<const h2*>(&B);
        #pragma unroll
        for (int q = 0; q < 4; ++q)
            hacc[q] = a2[q] * v0p + (b2[q] * v1p + hacc[q]);
    }
    if (e < end) {
        int   n0 = node_idx[e];
        _Float16 v0 = (_Float16)values[e];
        h2 v0p = {v0, v0};
        half8 A = x0h[(size_t)n0 * 16 + lane];
        const h2* a2 = reinterpret_cast<const h2*>(&A);
        #pragma unroll
        for (int q = 0; q < 4; ++q) hacc[q] = a2[q] * v0p + hacc[q];
    }

    __shared__ float red[128][9];   // +1 pad
    #pragma unroll
    for (int q = 0; q < 4; ++q) {
        red[tid][2 * q]     = (float)hacc[q][0];
        red[tid][2 * q + 1] = (float)hacc[q][1];
    }
    __syncthreads();
    // thread c owns channel c: contributions at red[sub*16 + (c>>3)][c&7]
    int c = tid;
    float s = 0.f;
    #pragma unroll
    for (int ss = 0; ss < 8; ++ss) s += red[ss * 16 + (c >> 3)][c & 7];
    m01h[(size_t)j * C + c] = (_Float16)s;
    float p = s * att[c];
    #pragma unroll
    for (int off = 32; off > 0; off >>= 1) p += __shfl_down(p, off, 64);
    __shared__ float pw[2];
    if ((tid & 63) == 0) pw[tid >> 6] = p;
    __syncthreads();
    if (tid == 0) s_edge[j] = pw[0] + pw[1];
}

// BH: per-bucket totals. Wave-private LDS histograms -> ~100k global adds.
__global__ __launch_bounds__(256) void k_bhist(
    const int* __restrict__ node_idx, int* __restrict__ btot)
{
    __shared__ int cnt4[4][NB];
    int tid = threadIdx.x;
    int w   = tid >> 6;
    for (int b = tid; b < 4 * NB; b += 256) (&cnt4[0][0])[b] = 0;
    __syncthreads();
    const int per = (NNZT + 255) / 256;   // 6250
    int e0 = blockIdx.x * per;
    int e1 = e0 + per; if (e1 > NNZT) e1 = NNZT;
    for (int e = e0 + tid; e < e1; e += 256)
        atomicAdd(&cnt4[w][node_idx[e] >> 8], 1);
    __syncthreads();
    for (int b = tid; b < NB; b += 256) {
        int cc = cnt4[0][b] + cnt4[1][b] + cnt4[2][b] + cnt4[3][b];
        if (cc) atomicAdd(&btot[b], cc);
    }
}

// BS: exclusive scan of 391 bucket totals -> bbase[0..NB], bcur init.
__global__ __launch_bounds__(512) void k_bscan(
    const int* __restrict__ btot, int* __restrict__ bbase, int* __restrict__ bcur)
{
    __shared__ int s[512];
    int tid = threadIdx.x;
    int v = (tid < NB) ? btot[tid] : 0;
    s[tid] = v;
    __syncthreads();
    for (int off = 1; off < 512; off <<= 1) {
        int t = (tid >= off) ? s[tid - off] : 0;
        __syncthreads();
        s[tid] += t;
        __syncthreads();
    }
    if (tid < NB) { bbase[tid] = s[tid] - v; bcur[tid] = s[tid] - v; }
    if (tid == NB - 1) bbase[NB] = s[tid];
}

// BinA: chunk-reserve scatter into bucket-ordered tmp arrays.
// Wave-private LDS counters (4x less contention), no staging buffer.
__global__ __launch_bounds__(256) void k_binA(
    const int*   __restrict__ node_idx,
    const int*   __restrict__ edge_idx,
    const float* __restrict__ values,
    const float* __restrict__ s_edge,
    const float* __restrict__ t_node,
    int*  __restrict__ bcur,
    int*  __restrict__ tmp_n,
    int2* __restrict__ tmp_jc)
{
    __shared__ int cnt4[4][NB];
    __shared__ int res4[4][NB];
    int tid = threadIdx.x;
    int w   = tid >> 6;
    for (int b = tid; b < 4 * NB; b += 256) (&cnt4[0][0])[b] = 0;
    __syncthreads();
    int e0 = blockIdx.x * EPB;
    int e1 = e0 + EPB; if (e1 > NNZT) e1 = NNZT;
    for (int e = e0 + tid; e < e1; e += 256)
        atomicAdd(&cnt4[w][node_idx[e] >> 8], 1);
    __syncthreads();
    for (int b = tid; b < NB; b += 256) {
        int c0 = cnt4[0][b], c1 = cnt4[1][b], c2 = cnt4[2][b], c3 = cnt4[3][b];
        int tot = c0 + c1 + c2 + c3;
        int r = tot ? atomicAdd(&bcur[b], tot) : 0;
        res4[0][b] = r;
        res4[1][b] = r + c0;
        res4[2][b] = r + c0 + c1;
        res4[3][b] = r + c0 + c1 + c2;
        cnt4[0][b] = 0; cnt4[1][b] = 0; cnt4[2][b] = 0; cnt4[3][b] = 0;
    }
    __syncthreads();
    for (int e = e0 + tid; e < e1; e += 256) {
        int n = node_idx[e];
        int b = n >> 8;
        int r = atomicAdd(&cnt4[w][b], 1);
        int pos = res4[w][b] + r;
        int j = edge_idx[e];
        float s = s_edge[j] + t_node[n];
        float coef = (s > 0.f ? s : expm1f(s)) * values[e];
        tmp_n[pos]  = n;
        tmp_jc[pos] = make_int2(j, __float_as_int(coef));
    }
}

// BinB: one block per bucket. Local LDS hist+scan derives per-node base/count
// (written out for k3), then scatters to exact per-node slots.
__global__ __launch_bounds__(256) void k_binB(
    const int*  __restrict__ tmp_n,
    const int2* __restrict__ tmp_jc,
    const int*  __restrict__ bbase,
    int*  __restrict__ base,
    int*  __restrict__ count,
    int2* __restrict__ jc)
{
    int b   = blockIdx.x;
    int tid = threadIdx.x;
    int n0  = b << 8;
    __shared__ int cnt[256], scn[256], cur[256];
    __shared__ int lo_s, hi_s;
    cnt[tid] = 0;
    if (tid == 0) { lo_s = bbase[b]; hi_s = bbase[b + 1]; }
    __syncthreads();
    int lo = lo_s, hi = hi_s;
    for (int i = lo + tid; i < hi; i += 256)
        atomicAdd(&cnt[tmp_n[i] - n0], 1);
    __syncthreads();
    int v = cnt[tid];
    scn[tid] = v;
    __syncthreads();
    for (int off = 1; off < 256; off <<= 1) {
        int t = (tid >= off) ? scn[tid - off] : 0;
        __syncthreads();
        scn[tid] += t;
        __syncthreads();
    }
    int excl = scn[tid] - v;
    int nn = n0 + tid;
    if (nn < N_NODES) { base[nn] = lo + excl; count[nn] = v; }
    cur[tid] = lo + excl;
    __syncthreads();
    for (int i = lo + tid; i < hi; i += 256) {
        int n = tmp_n[i];
        int pos = atomicAdd(&cur[n - n0], 1);
        jc[pos] = tmp_jc[i];
    }
}

// K3: gather-accumulate per destination node (atomic-free), fp16 rows;
// parallel epilogue, emits yh fp16 (coalesced half stores).
__global__ __launch_bounds__(128) void k3_gather(
    const half8* __restrict__ m01h,
    const int2*  __restrict__ jc,
    const int*   __restrict__ base,
    const int*   __restrict__ count,
    _Float16* __restrict__ yh)
{
    int n    = blockIdx.x;
    int tid  = threadIdx.x;
    int sub  = tid >> 4;
    int lane = tid & 15;
    int b    = base[n];
    int cnt  = count[n];

    float facc[8];
    #pragma unroll
    for (int q = 0; q < 8; ++q) facc[q] = 0.f;

    int i = sub;
    for (; i + 8 < cnt; i += 16) {
        int2 p0 = jc[b + i];
        int2 p1 = jc[b + i + 8];
        float c0 = __int_as_float(p0.y);
        float c1 = __int_as_float(p1.y);
        half8 a = m01h[(size_t)p0.x * 16 + lane];
        half8 bb = m01h[(size_t)p1.x * 16 + lane];
        #pragma unroll
        for (int q = 0; q < 8; ++q)
            facc[q] += c0 * (float)a[q] + c1 * (float)bb[q];
    }
    if (i < cnt) {
        int2 p0 = jc[b + i];
        float c0 = __int_as_float(p0.y);
        half8 a = m01h[(size_t)p0.x * 16 + lane];
        #pragma unroll
        for (int q = 0; q < 8; ++q) facc[q] += c0 * (float)a[q];
    }

    __shared__ float red[128][9];
    #pragma unroll
    for (int q = 0; q < 8; ++q) red[tid][q] = facc[q];
    __syncthreads();
    int c = tid;
    float s = 0.f;
    #pragma unroll
    for (int ss = 0; ss < 8; ++ss) s += red[ss * 16 + (c >> 3)][c & 7];
    yh[(size_t)n * C + c] = (_Float16)s;
}

// K4: out = yh @ W via MFMA f16. One wave per 16 rows; 8 col-tiles x 4 k-chunks.
__global__ __launch_bounds__(64) void k4_mfma(
    const _Float16* __restrict__ yh,   // N_NODES x C row-major
    const _Float16* __restrict__ wt,   // wt[n*C+k] = W[k][n]
    float* __restrict__ out)
{
    int lane = threadIdx.x;            // 0..63
    int m    = lane & 15;
    int quad = lane >> 4;              // 0..3
    int rb   = blockIdx.x * 16;
    const _Float16* yrow = yh + (size_t)(rb + m) * C + quad * 8;
    half8 a[4];
    #pragma unroll
    for (int kc = 0; kc < 4; ++kc)
        a[kc] = *reinterpret_cast<const half8*>(yrow + kc * 32);
    #pragma unroll
    for (int ct = 0; ct < 8; ++ct) {
        const _Float16* wrow = wt + (size_t)(ct * 16 + m) * C + quad * 8;
        f32x4 acc = {0.f, 0.f, 0.f, 0.f};
        #pragma unroll
        for (int kc = 0; kc < 4; ++kc) {
            half8 b = *reinterpret_cast<const half8*>(wrow + kc * 32);
            acc = __builtin_amdgcn_mfma_f32_16x16x32_f16(a[kc], b, acc, 0, 0, 0);
        }
        int orow = rb + quad * 4;
        int ocol = ct * 16 + m;
        #pragma unroll
        for (int r = 0; r < 4; ++r)
            out[(size_t)(orow + r) * C + ocol] = acc[r];
    }
}

extern "C" void kernel_launch(void* const* d_in, const int* in_sizes, int n_in,
                              void* d_out, int out_size, void* d_ws, size_t ws_size,
                              hipStream_t stream)
{
    const float* x0       = (const float*)d_in[0];
    const int*   node_idx = (const int*)  d_in[1];
    const int*   edge_idx = (const int*)  d_in[2];
    const float* values   = (const float*)d_in[3];
    const float* W        = (const float*)d_in[4];
    const float* att      = (const float*)d_in[5];
    float* out = (float*)d_out;

    // d_out layout: [x0h 25.6MB][m01h 25.6MB]. x0h dead after k2 -> reused for
    // binning temporaries (19.2 MB). All dead before k4 writes final output.
    _Float16* x0h_s  = (_Float16*)d_out;
    _Float16* m01h_s = x0h_s + (size_t)N_NODES * C;
    int*  tmp_n  = (int*)d_out;                               // 6.4 MB
    int2* tmp_jc = (int2*)((char*)d_out + (size_t)NNZT * 4);  // 12.8 MB

    char*  p   = (char*)d_ws;
    _Float16* yh    = (_Float16*)p; p += (size_t)N_NODES * C * sizeof(_Float16); // 25.6 MB
    float* t_node   = (float*)p;  p += N_NODES * sizeof(float);
    float* s_edge   = (float*)p;  p += N_EDGES * sizeof(float);
    int*   count    = (int*)p;    p += N_NODES * sizeof(int);
    int*   base     = (int*)p;    p += N_NODES * sizeof(int);
    int*   btot     = (int*)p;    p += 512 * sizeof(int);
    int*   bbase    = (int*)p;    p += 512 * sizeof(int);
    int*   bcur     = (int*)p;    p += 512 * sizeof(int);
    int*   row_start= (int*)p;    p += (N_EDGES + 1) * sizeof(int);
    _Float16* wt    = (_Float16*)p; p += (size_t)C * C * sizeof(_Float16);       // 32 KB
    int2*  jc       = (int2*)p;   p += (size_t)NNZT * sizeof(int2);              // 12.8 MB

    hipMemsetAsync(btot, 0, NB * sizeof(int), stream);

    k1_node_dot<<<N_NODES, 128, 0, stream>>>(x0, att, t_node, x0h_s);
    k_rowptr<<<(NNZT + 255) / 256, 256, 0, stream>>>(edge_idx, row_start);
    k_wcvt  <<<(C * C + 255) / 256, 256, 0, stream>>>(W, wt);
    k2_edge_msg<<<N_EDGES, 128, 0, stream>>>((const half8*)x0h_s, node_idx, row_start,
                                             values, att, m01h_s, s_edge);

    k_bhist<<<256, 256, 0, stream>>>(node_idx, btot);
    k_bscan<<<1, 512, 0, stream>>>(btot, bbase, bcur);
    k_binA<<<(NNZT + EPB - 1) / EPB, 256, 0, stream>>>(node_idx, edge_idx, values,
                                                       s_edge, t_node, bcur, tmp_n, tmp_jc);
    k_binB<<<NB, 256, 0, stream>>>(tmp_n, tmp_jc, bbase, base, count, jc);

    k3_gather<<<N_NODES, 128, 0, stream>>>((const half8*)m01h_s, jc, base, count, yh);
    k4_mfma<<<N_NODES / 16, 64, 0, stream>>>(yh, wt, out);
}